// Round 2
// baseline (328.763 us; speedup 1.0000x reference)
//
#include <hip/hip_runtime.h>

#define BB 4
#define SQn 2048
#define SS 2048
#define DM 256
#define DH 32

typedef unsigned short u16;
typedef unsigned int u32;
typedef _Float16 f16;
typedef __attribute__((ext_vector_type(8))) f16 f16x8;
typedef __attribute__((ext_vector_type(8))) short s16x8;
typedef __attribute__((ext_vector_type(4))) float f32x4;
typedef __attribute__((ext_vector_type(4))) u32 u32x4;
typedef __attribute__((ext_vector_type(2))) u32 u32x2;

__device__ __forceinline__ float bf2f(u16 x){ u32 u=((u32)x)<<16; return __builtin_bit_cast(float,u); }
__device__ __forceinline__ u16 f2bf(float f){ u32 u=__builtin_bit_cast(u32,f); u32 r=(u+0x7fffu+((u>>16)&1u))>>16; return (u16)r; }

// Load 8 consecutive elements as f16 from bf16 (fl=0) or fp32 (fl=1) buffer.
__device__ __forceinline__ f16x8 ld8(const void* p, size_t off, int fl)
{
    f16x8 r;
    if (fl) {
        const float* f = (const float*)p + off;
        f32x4 a = *(const f32x4*)f;
        f32x4 b = *(const f32x4*)(f + 4);
        #pragma unroll
        for (int i = 0; i < 4; ++i) { r[i] = (f16)a[i]; r[4+i] = (f16)b[i]; }
    } else {
        const u16* s = (const u16*)p + off;
        u32x4 v = *(const u32x4*)s;
        #pragma unroll
        for (int i = 0; i < 4; ++i) {
            u32 x = v[i];
            r[2*i]   = (f16)bf2f((u16)(x & 0xffff));
            r[2*i+1] = (f16)bf2f((u16)(x >> 16));
        }
    }
    return r;
}
__device__ __forceinline__ float ld1(const void* p, int idx, int fl)
{ return fl ? ((const float*)p)[idx] : bf2f(((const u16*)p)[idx]); }

// 4 consecutive f32 from bf16/fp32 buffer.
__device__ __forceinline__ f32x4 ld_d4(const void* p, int fl, size_t off)
{
    f32x4 r;
    if (fl) r = *(const f32x4*)((const float*)p + off);
    else {
        u32x2 v = *(const u32x2*)((const u16*)p + off);
        r[0]=bf2f((u16)(v[0]&0xffff)); r[1]=bf2f((u16)(v[0]>>16));
        r[2]=bf2f((u16)(v[1]&0xffff)); r[3]=bf2f((u16)(v[1]>>16));
    }
    return r;
}

// ---------------------------------------------------------------------------
// Dtype detection: 0 = bf16 inputs, 1 = fp32 inputs.
// ---------------------------------------------------------------------------
__global__ void detect_kernel(const u32* __restrict__ q, int* __restrict__ flag)
{
    int t = threadIdx.x;                 // 256
    u32 w = q[t];
    u32 e = (w >> 7) & 0xFFu;
    int vote = ((e >= 0x70u && e <= 0x85u) || ((w & 0xFFFFu) == 0u)) ? 1 : 0;
    #pragma unroll
    for (int d = 1; d < 64; d <<= 1) vote += __shfl_xor(vote, d);
    __shared__ int ps[4];
    if ((t & 63) == 0) ps[t >> 6] = vote;
    __syncthreads();
    if (t == 0) *flag = ((ps[0]+ps[1]+ps[2]+ps[3]) >= 128) ? 0 : 1;
}

// ---------------------------------------------------------------------------
// Kernel A: fused projections (f16 MFMA).  q->qf f16, k->kf f16,
// v->vt bf16 TRANSPOSED [b][d][s].
// ---------------------------------------------------------------------------
__global__ __launch_bounds__(256) void proj_kernel(
    const int* __restrict__ flag,
    const void* __restrict__ query, const void* __restrict__ values, const void* __restrict__ tkeys,
    const void* __restrict__ Wq, const void* __restrict__ Wqb,
    const void* __restrict__ Wk, const void* __restrict__ Wkb,
    const void* __restrict__ Wv, const void* __restrict__ Wvb,
    f16* __restrict__ qf, f16* __restrict__ kf, u16* __restrict__ vt)
{
    int fl = *flag;
    int bx = blockIdx.x;
    const void *X, *W, *Bi; int mode, rowbase;
    if (bx < 128)      { X=query;  W=Wq; Bi=Wqb; mode=0; rowbase=bx*64; }
    else if (bx < 256) { X=values; W=Wv; Bi=Wvb; mode=2; rowbase=(bx-128)*64; }
    else               { X=tkeys;  W=Wk; Bi=Wkb; mode=1; rowbase=(bx-256)*64; }
    int colbase = blockIdx.y * 64;

    __shared__ f16 Xs[64][40];
    __shared__ f16 Ws[64][40];
    __shared__ u16 Os[64][72];

    int t = threadIdx.x;
    int lane = t & 63, w = t >> 6;
    int quad = lane >> 4, l15 = lane & 15;

    const f32x4 fz = {0.f,0.f,0.f,0.f};
    f32x4 acc[4] = {fz,fz,fz,fz};

    for (int ks = 0; ks < 8; ++ks) {
        int k0 = ks * 32;
        {
            int row = t >> 2, ch = (t & 3) * 8;
            f16x8 xv = ld8(X, (size_t)(rowbase+row)*DM + k0 + ch, fl);
            f16x8 wv = ld8(W, (size_t)(colbase+row)*DM + k0 + ch, fl);
            *(f16x8*)(&Xs[row][ch]) = xv;
            *(f16x8*)(&Ws[row][ch]) = wv;
        }
        __syncthreads();
        f16x8 a = *(const f16x8*)(&Xs[w*16 + l15][quad*8]);
        #pragma unroll
        for (int nt = 0; nt < 4; ++nt) {
            f16x8 bfr = *(const f16x8*)(&Ws[nt*16 + l15][quad*8]);
            acc[nt] = __builtin_amdgcn_mfma_f32_16x16x32_f16(a, bfr, acc[nt], 0, 0, 0);
        }
        __syncthreads();
    }

    if (mode == 2) {
        // bf16 transposed store: (m, n) -> vt[(b*256+n)*2048 + s]
        #pragma unroll
        for (int nt = 0; nt < 4; ++nt) {
            int col = colbase + nt*16 + l15;
            float bv = ld1(Bi, col, fl);
            int m = rowbase + w*16 + quad*4;
            int b = m >> 11, s = m & 2047;
            u32x2 pk;
            pk[0] = (u32)f2bf(acc[nt][0]+bv) | ((u32)f2bf(acc[nt][1]+bv) << 16);
            pk[1] = (u32)f2bf(acc[nt][2]+bv) | ((u32)f2bf(acc[nt][3]+bv) << 16);
            *(u32x2*)(vt + ((size_t)(b*DM + col))*SS + s) = pk;
        }
    } else {
        f16* dst = (mode == 0) ? qf : kf;
        #pragma unroll
        for (int nt = 0; nt < 4; ++nt) {
            int col = nt*16 + l15;
            float bv = ld1(Bi, colbase + col, fl);
            #pragma unroll
            for (int r = 0; r < 4; ++r)
                Os[w*16 + quad*4 + r][col] = __builtin_bit_cast(u16, (f16)(acc[nt][r] + bv));
        }
        __syncthreads();
        #pragma unroll
        for (int p = 0; p < 2; ++p) {
            int rr = (t >> 3) + p*32;
            int ch = (t & 7) * 8;
            u32x4 v = *(const u32x4*)(&Os[rr][ch]);
            *(u32x4*)(dst + (size_t)(rowbase+rr)*DM + colbase + ch) = v;
        }
    }
}

// ---------------------------------------------------------------------------
// Kernel B: rs[row] = (1/sqrt(32)) / sum_k 1/(dist[row][k] + 1e-9)
// ---------------------------------------------------------------------------
__global__ __launch_bounds__(256) void dwsum_kernel(
    const int* __restrict__ flag, const void* __restrict__ dist, float* __restrict__ rs)
{
    int fl = *flag;
    int row = blockIdx.x;
    int t = threadIdx.x;
    float s = 0.f;
    if (fl) {
        const float* p = (const float*)dist + (size_t)row * SS + t*8;
        f32x4 a = *(const f32x4*)p;
        f32x4 b = *(const f32x4*)(p + 4);
        #pragma unroll
        for (int i = 0; i < 4; ++i) { s += 1.0f/(a[i]+1e-9f); s += 1.0f/(b[i]+1e-9f); }
    } else {
        const u16* p = (const u16*)dist + (size_t)row * SS + t*8;
        u32x4 v = *(const u32x4*)p;
        #pragma unroll
        for (int i = 0; i < 4; ++i) {
            u32 x = v[i];
            s += 1.0f / (bf2f((u16)(x & 0xffff)) + 1e-9f);
            s += 1.0f / (bf2f((u16)(x >> 16))    + 1e-9f);
        }
    }
    #pragma unroll
    for (int d = 1; d < 64; d <<= 1) s += __shfl_xor(s, d);
    __shared__ float ps[4];
    if ((t & 63) == 0) ps[t >> 6] = s;
    __syncthreads();
    if (t == 0) rs[row] = 0.17677669529663687f / (ps[0] + ps[1] + ps[2] + ps[3]);
}

// ---------------------------------------------------------------------------
// Kernel C: flash attention (no-max softmax, S^T orientation, zero in-loop
// barriers) + fused fc.  1 block = (b, 16 q-rows), 8 waves = 8 heads.
// Grid 128x4 = 512 blocks -> 2 blocks/CU (was 1) to fix wave starvation.
// ---------------------------------------------------------------------------
#define LDP 40
#define LDO 264

struct Frags { f16x8 bk[2]; s16x8 bv[2]; f32x4 dd[2]; };

__device__ __forceinline__ Frags load_frags(
    const f16* kf, const u16* vtg, const void* dist, int fl,
    int b, int q0, int h, int kb, int l15, int quad)
{
    Frags f;
    #pragma unroll
    for (int nt = 0; nt < 2; ++nt)
        f.bk[nt] = *(const f16x8*)(kf + (size_t)(kb + nt*16 + l15)*DM + h*DH + quad*8);
    #pragma unroll
    for (int nt = 0; nt < 2; ++nt)
        f.bv[nt] = __builtin_bit_cast(s16x8,
            *(const u32x4*)(vtg + ((size_t)(b*DM + h*DH + nt*16 + l15))*SS + kb + quad*8));
    #pragma unroll
    for (int nt = 0; nt < 2; ++nt)
        f.dd[nt] = ld_d4(dist, fl,
            ((size_t)(b*SQn + q0 + l15))*SS + kb + nt*16 + quad*4);
    return f;
}

__global__ __launch_bounds__(512) void attn_kernel(
    const int* __restrict__ flag,
    const void* __restrict__ dist, const float* __restrict__ rs,
    const f16* __restrict__ qf, const f16* __restrict__ kf, const u16* __restrict__ vtg,
    const void* __restrict__ fcw, const void* __restrict__ fcb,
    void* __restrict__ out)
{
    __shared__ __align__(16) char smem[25344];
    // loop phase: per-wave P slice [16][LDP] (bf16 bits), 1280 B each, 8 waves (10240 B)
    // epilogue:   Ol f16 [16][LDO] at 0 (8448 B); OutF f32 [16][LDO] at 8448 (16896 B)

    int fl = *flag;
    int t = threadIdx.x;
    int w = t >> 6, lane = t & 63;
    int quad = lane >> 4, l15 = lane & 15;
    int b = blockIdx.y, q0 = blockIdx.x * 16;
    int h = w;

    u16* Pw = (u16*)(smem + w * 1280);

    float rsq = rs[b*SQn + q0 + l15];

    f16x8 aq = *(const f16x8*)(qf + (size_t)(b*SQn + q0 + l15)*DM + h*DH + quad*8);

    // ones-column B-fragment (bf16): B[k][0]=1, else 0 -> row-sum via MFMA
    u32 ov = (l15 == 0) ? 0x3F803F80u : 0u;
    u32x4 ovv = {ov, ov, ov, ov};
    s16x8 ones = __builtin_bit_cast(s16x8, ovv);

    const f32x4 fz = {0.f,0.f,0.f,0.f};
    f32x4 o[2] = {fz,fz};
    f32x4 lacc = fz;

    Frags cur = load_frags(kf, vtg, dist, fl, b, q0, h, 0, l15, quad);

    for (int kt = 0; kt < 64; ++kt) {
        int kbn = ((kt + 1) & 63) * 32;          // wrap: last prefetch reads valid (unused) memory
        Frags nxt = load_frags(kf, vtg, dist, fl, b, q0, h, kbn, l15, quad);

        // S^T = K·Q^T : C elem (key = nt*16+quad*4+r, q = l15)
        f32x4 st[2];
        #pragma unroll
        for (int nt = 0; nt < 2; ++nt)
            st[nt] = __builtin_amdgcn_mfma_f32_16x16x32_f16(cur.bk[nt], aq, fz, 0, 0, 0);

        // dw (register-resident), exp (no max: bf16 P has f32 exponent range), pack, LDS
        #pragma unroll
        for (int nt = 0; nt < 2; ++nt) {
            f32x4 d = cur.dd[nt];
            u32 pb[4];
            #pragma unroll
            for (int r = 0; r < 4; ++r) {
                float dwv = rsq * __builtin_amdgcn_rcpf(d[r] + 1e-9f);
                float p = __expf(st[nt][r] * dwv);
                pb[r] = __builtin_bit_cast(u32, p);
            }
            u32x2 pk;
            pk[0] = __builtin_amdgcn_perm(pb[1], pb[0], 0x07060302u);  // [p1.hi16|p0.hi16]
            pk[1] = __builtin_amdgcn_perm(pb[3], pb[2], 0x07060302u);
            *(u32x2*)(Pw + l15*LDP + nt*16 + quad*4) = pk;
        }
        __asm__ __volatile__("" ::: "memory");   // order the per-wave LDS transpose

        // P @ [V | 1] in bf16 (l arrives in o's C-layout; same rounded p in num & denom)
        s16x8 ap = *(const s16x8*)(Pw + l15*LDP + quad*8);
        lacc = __builtin_amdgcn_mfma_f32_16x16x32_bf16(ap, ones, lacc, 0, 0, 0);
        #pragma unroll
        for (int nt = 0; nt < 2; ++nt)
            o[nt] = __builtin_amdgcn_mfma_f32_16x16x32_bf16(ap, cur.bv[nt], o[nt], 0, 0, 0);
        cur = nxt;
    }

    // ---- normalize: l for row (quad,r) lives at lane (l15=0, quad), col 0 ----
    #pragma unroll
    for (int r = 0; r < 4; ++r) {
        float lv = __shfl(lacc[r], lane & 48);
        float inv = 1.0f / lv;
        o[0][r] *= inv;
        o[1][r] *= inv;
    }

    // ---- epilogue: fused fc ----
    __syncthreads();                       // all waves done with P slices
    f16* Ol = (f16*)smem;                  // [16][LDO]
    #pragma unroll
    for (int nt = 0; nt < 2; ++nt)
        #pragma unroll
        for (int r = 0; r < 4; ++r)
            Ol[(quad*4 + r)*LDO + h*DH + nt*16 + l15] = (f16)o[nt][r];
    __syncthreads();

    f32x4 c[2] = {fz,fz};
    for (int ks = 0; ks < 8; ++ks) {
        f16x8 a2 = *(const f16x8*)(Ol + l15*LDO + ks*32 + quad*8);
        #pragma unroll
        for (int nt = 0; nt < 2; ++nt) {
            int n = w*32 + nt*16 + l15;
            f16x8 bw = ld8(fcw, (size_t)n*DM + ks*32 + quad*8, fl);
            c[nt] = __builtin_amdgcn_mfma_f32_16x16x32_f16(a2, bw, c[nt], 0, 0, 0);
        }
    }
    float* OutF = (float*)(smem + 8448);   // [16][LDO] f32, disjoint from Ol
    #pragma unroll
    for (int nt = 0; nt < 2; ++nt) {
        int n = w*32 + nt*16 + l15;
        float bv = ld1(fcb, n, fl);
        #pragma unroll
        for (int r = 0; r < 4; ++r)
            OutF[(quad*4 + r)*LDO + n] = c[nt][r] + bv;
    }
    __syncthreads();
    if (fl) {
        float* of = (float*)out;
        #pragma unroll
        for (int p = 0; p < 2; ++p) {
            int idx = (t + p*512) * 4;
            int row = idx >> 8, col = idx & 255;
            f32x4 v = *(const f32x4*)(OutF + row*LDO + col);
            *(f32x4*)(of + ((size_t)(b*SQn + q0 + row))*DM + col) = v;
        }
    } else {
        u16* ob = (u16*)out;
        {
            int idx = t * 8;
            int row = idx >> 8, col = idx & 255;
            f32x4 v0 = *(const f32x4*)(OutF + row*LDO + col);
            f32x4 v1 = *(const f32x4*)(OutF + row*LDO + col + 4);
            u32x4 pk;
            pk[0] = (u32)f2bf(v0[0]) | ((u32)f2bf(v0[1]) << 16);
            pk[1] = (u32)f2bf(v0[2]) | ((u32)f2bf(v0[3]) << 16);
            pk[2] = (u32)f2bf(v1[0]) | ((u32)f2bf(v1[1]) << 16);
            pk[3] = (u32)f2bf(v1[2]) | ((u32)f2bf(v1[3]) << 16);
            *(u32x4*)(ob + ((size_t)(b*SQn + q0 + row))*DM + col) = pk;
        }
    }
}

// ---------------------------------------------------------------------------
extern "C" void kernel_launch(void* const* d_in, const int* in_sizes, int n_in,
                              void* d_out, int out_size, void* d_ws, size_t ws_size,
                              hipStream_t stream)
{
    const void* query  = d_in[0];
    const void* values = d_in[1];
    const void* dist   = d_in[2];
    const void* Wq     = d_in[3];
    const void* Wqb    = d_in[4];
    const void* Wk     = d_in[5];
    const void* Wkb    = d_in[6];
    const void* Wv     = d_in[7];
    const void* Wvb    = d_in[8];
    const void* fcw    = d_in[9];
    const void* fcb    = d_in[10];
    const void* tkeys  = d_in[11];

    char* ws   = (char*)d_ws;
    f16*  qf   = (f16*)ws;                     // 4 MB  [B*SQ][256] f16
    f16*  kf   = (f16*)(ws + (4u << 20));      // 1 MB  [S][256] f16
    u16*  vt   = (u16*)(ws + (5u << 20));      // 4 MB  [b][d][s] bf16
    float* rsp = (float*)(ws + (9u << 20));    // 32 KB [B*SQ]
    int*  flag = (int*)(ws + (9u << 20) + 32768);

    detect_kernel<<<1, 256, 0, stream>>>((const u32*)query, flag);
    proj_kernel<<<dim3(288, 4), 256, 0, stream>>>(flag, query, values, tkeys,
                                                  Wq, Wqb, Wk, Wkb, Wv, Wvb,
                                                  qf, kf, vt);
    dwsum_kernel<<<dim3(BB * SQn), 256, 0, stream>>>(flag, dist, rsp);
    attn_kernel<<<dim3(128, 4), 512, 0, stream>>>(flag, dist, rsp, qf, kf, vt, fcw, fcb, d_out);
}

// Round 3
// 293.381 us; speedup vs baseline: 1.1206x; 1.1206x over previous
//
#include <hip/hip_runtime.h>

#define BB 4
#define SQn 2048
#define SS 2048
#define DM 256
#define DH 32

typedef unsigned short u16;
typedef unsigned int u32;
typedef _Float16 f16;
typedef __attribute__((ext_vector_type(8))) f16 f16x8;
typedef __attribute__((ext_vector_type(8))) short s16x8;
typedef __attribute__((ext_vector_type(4))) float f32x4;
typedef __attribute__((ext_vector_type(4))) u32 u32x4;
typedef __attribute__((ext_vector_type(2))) u32 u32x2;

__device__ __forceinline__ float bf2f(u16 x){ u32 u=((u32)x)<<16; return __builtin_bit_cast(float,u); }
__device__ __forceinline__ u16 f2bf(float f){ u32 u=__builtin_bit_cast(u32,f); u32 r=(u+0x7fffu+((u>>16)&1u))>>16; return (u16)r; }

// Load 8 consecutive elements as f16 from bf16 (fl=0) or fp32 (fl=1) buffer.
__device__ __forceinline__ f16x8 ld8(const void* p, size_t off, int fl)
{
    f16x8 r;
    if (fl) {
        const float* f = (const float*)p + off;
        f32x4 a = *(const f32x4*)f;
        f32x4 b = *(const f32x4*)(f + 4);
        #pragma unroll
        for (int i = 0; i < 4; ++i) { r[i] = (f16)a[i]; r[4+i] = (f16)b[i]; }
    } else {
        const u16* s = (const u16*)p + off;
        u32x4 v = *(const u32x4*)s;
        #pragma unroll
        for (int i = 0; i < 4; ++i) {
            u32 x = v[i];
            r[2*i]   = (f16)bf2f((u16)(x & 0xffff));
            r[2*i+1] = (f16)bf2f((u16)(x >> 16));
        }
    }
    return r;
}
__device__ __forceinline__ float ld1(const void* p, int idx, int fl)
{ return fl ? ((const float*)p)[idx] : bf2f(((const u16*)p)[idx]); }

// 4 consecutive f32 from bf16/fp32 buffer.
__device__ __forceinline__ f32x4 ld_d4(const void* p, int fl, size_t off)
{
    f32x4 r;
    if (fl) r = *(const f32x4*)((const float*)p + off);
    else {
        u32x2 v = *(const u32x2*)((const u16*)p + off);
        r[0]=bf2f((u16)(v[0]&0xffff)); r[1]=bf2f((u16)(v[0]>>16));
        r[2]=bf2f((u16)(v[1]&0xffff)); r[3]=bf2f((u16)(v[1]>>16));
    }
    return r;
}

// ---------------------------------------------------------------------------
// Dtype detection: 0 = bf16 inputs, 1 = fp32 inputs.
// ---------------------------------------------------------------------------
__global__ void detect_kernel(const u32* __restrict__ q, int* __restrict__ flag)
{
    int t = threadIdx.x;                 // 256
    u32 w = q[t];
    u32 e = (w >> 7) & 0xFFu;
    int vote = ((e >= 0x70u && e <= 0x85u) || ((w & 0xFFFFu) == 0u)) ? 1 : 0;
    #pragma unroll
    for (int d = 1; d < 64; d <<= 1) vote += __shfl_xor(vote, d);
    __shared__ int ps[4];
    if ((t & 63) == 0) ps[t >> 6] = vote;
    __syncthreads();
    if (t == 0) *flag = ((ps[0]+ps[1]+ps[2]+ps[3]) >= 128) ? 0 : 1;
}

// ---------------------------------------------------------------------------
// Kernel A: fused projections (f16 MFMA).  q->qf f16, k->kf f16,
// v->vt bf16 TRANSPOSED [b][d][s].
// ---------------------------------------------------------------------------
__global__ __launch_bounds__(256) void proj_kernel(
    const int* __restrict__ flag,
    const void* __restrict__ query, const void* __restrict__ values, const void* __restrict__ tkeys,
    const void* __restrict__ Wq, const void* __restrict__ Wqb,
    const void* __restrict__ Wk, const void* __restrict__ Wkb,
    const void* __restrict__ Wv, const void* __restrict__ Wvb,
    f16* __restrict__ qf, f16* __restrict__ kf, u16* __restrict__ vt)
{
    int fl = *flag;
    int bx = blockIdx.x;
    const void *X, *W, *Bi; int mode, rowbase;
    if (bx < 128)      { X=query;  W=Wq; Bi=Wqb; mode=0; rowbase=bx*64; }
    else if (bx < 256) { X=values; W=Wv; Bi=Wvb; mode=2; rowbase=(bx-128)*64; }
    else               { X=tkeys;  W=Wk; Bi=Wkb; mode=1; rowbase=(bx-256)*64; }
    int colbase = blockIdx.y * 64;

    __shared__ f16 Xs[64][40];
    __shared__ f16 Ws[64][40];
    __shared__ u16 Os[64][72];

    int t = threadIdx.x;
    int lane = t & 63, w = t >> 6;
    int quad = lane >> 4, l15 = lane & 15;

    const f32x4 fz = {0.f,0.f,0.f,0.f};
    f32x4 acc[4] = {fz,fz,fz,fz};

    for (int ks = 0; ks < 8; ++ks) {
        int k0 = ks * 32;
        {
            int row = t >> 2, ch = (t & 3) * 8;
            f16x8 xv = ld8(X, (size_t)(rowbase+row)*DM + k0 + ch, fl);
            f16x8 wv = ld8(W, (size_t)(colbase+row)*DM + k0 + ch, fl);
            *(f16x8*)(&Xs[row][ch]) = xv;
            *(f16x8*)(&Ws[row][ch]) = wv;
        }
        __syncthreads();
        f16x8 a = *(const f16x8*)(&Xs[w*16 + l15][quad*8]);
        #pragma unroll
        for (int nt = 0; nt < 4; ++nt) {
            f16x8 bfr = *(const f16x8*)(&Ws[nt*16 + l15][quad*8]);
            acc[nt] = __builtin_amdgcn_mfma_f32_16x16x32_f16(a, bfr, acc[nt], 0, 0, 0);
        }
        __syncthreads();
    }

    if (mode == 2) {
        // bf16 transposed store: (m, n) -> vt[(b*256+n)*2048 + s]
        #pragma unroll
        for (int nt = 0; nt < 4; ++nt) {
            int col = colbase + nt*16 + l15;
            float bv = ld1(Bi, col, fl);
            int m = rowbase + w*16 + quad*4;
            int b = m >> 11, s = m & 2047;
            u32x2 pk;
            pk[0] = (u32)f2bf(acc[nt][0]+bv) | ((u32)f2bf(acc[nt][1]+bv) << 16);
            pk[1] = (u32)f2bf(acc[nt][2]+bv) | ((u32)f2bf(acc[nt][3]+bv) << 16);
            *(u32x2*)(vt + ((size_t)(b*DM + col))*SS + s) = pk;
        }
    } else {
        f16* dst = (mode == 0) ? qf : kf;
        #pragma unroll
        for (int nt = 0; nt < 4; ++nt) {
            int col = nt*16 + l15;
            float bv = ld1(Bi, colbase + col, fl);
            #pragma unroll
            for (int r = 0; r < 4; ++r)
                Os[w*16 + quad*4 + r][col] = __builtin_bit_cast(u16, (f16)(acc[nt][r] + bv));
        }
        __syncthreads();
        #pragma unroll
        for (int p = 0; p < 2; ++p) {
            int rr = (t >> 3) + p*32;
            int ch = (t & 7) * 8;
            u32x4 v = *(const u32x4*)(&Os[rr][ch]);
            *(u32x4*)(dst + (size_t)(rowbase+rr)*DM + colbase + ch) = v;
        }
    }
}

// ---------------------------------------------------------------------------
// Kernel B: rs[row] = (1/sqrt(32)) / sum_k 1/(dist[row][k] + 1e-9)
// ---------------------------------------------------------------------------
__global__ __launch_bounds__(256) void dwsum_kernel(
    const int* __restrict__ flag, const void* __restrict__ dist, float* __restrict__ rs)
{
    int fl = *flag;
    int row = blockIdx.x;
    int t = threadIdx.x;
    float s = 0.f;
    if (fl) {
        const float* p = (const float*)dist + (size_t)row * SS + t*8;
        f32x4 a = *(const f32x4*)p;
        f32x4 b = *(const f32x4*)(p + 4);
        #pragma unroll
        for (int i = 0; i < 4; ++i) { s += 1.0f/(a[i]+1e-9f); s += 1.0f/(b[i]+1e-9f); }
    } else {
        const u16* p = (const u16*)dist + (size_t)row * SS + t*8;
        u32x4 v = *(const u32x4*)p;
        #pragma unroll
        for (int i = 0; i < 4; ++i) {
            u32 x = v[i];
            s += 1.0f / (bf2f((u16)(x & 0xffff)) + 1e-9f);
            s += 1.0f / (bf2f((u16)(x >> 16))    + 1e-9f);
        }
    }
    #pragma unroll
    for (int d = 1; d < 64; d <<= 1) s += __shfl_xor(s, d);
    __shared__ float ps[4];
    if ((t & 63) == 0) ps[t >> 6] = s;
    __syncthreads();
    if (t == 0) rs[row] = 0.17677669529663687f / (ps[0] + ps[1] + ps[2] + ps[3]);
}

// ---------------------------------------------------------------------------
// Kernel C: flash attention (no-max softmax, S^T orientation, zero in-loop
// barriers) + fused fc.  1 block = (b, 32 q-rows), 16 waves = 8 heads x 2
// k-halves (no-max softmax => k-split combines by plain addition).
// 1024 threads -> 4 waves/SIMD for latency hiding at round-0 traffic.
// ---------------------------------------------------------------------------
#define LDP 40
#define LDO 264
#define OL_OFF  49152
#define OUTF_OFF 66048

struct Frags { f16x8 bk[2]; s16x8 bv[2]; f32x4 dd[2][2]; };

__device__ __forceinline__ Frags load_frags(
    const f16* kf, const u16* vtg, const void* dist, int fl,
    int b, int q0, int h, int kb, int l15, int quad)
{
    Frags f;
    #pragma unroll
    for (int nt = 0; nt < 2; ++nt)
        f.bk[nt] = *(const f16x8*)(kf + (size_t)(kb + nt*16 + l15)*DM + h*DH + quad*8);
    #pragma unroll
    for (int nt = 0; nt < 2; ++nt)
        f.bv[nt] = __builtin_bit_cast(s16x8,
            *(const u32x4*)(vtg + ((size_t)(b*DM + h*DH + nt*16 + l15))*SS + kb + quad*8));
    #pragma unroll
    for (int mt = 0; mt < 2; ++mt)
        #pragma unroll
        for (int nt = 0; nt < 2; ++nt)
            f.dd[mt][nt] = ld_d4(dist, fl,
                ((size_t)(b*SQn + q0 + mt*16 + l15))*SS + kb + nt*16 + quad*4);
    return f;
}

__global__ __launch_bounds__(1024) void attn_kernel(
    const int* __restrict__ flag,
    const void* __restrict__ dist, const float* __restrict__ rs,
    const f16* __restrict__ qf, const f16* __restrict__ kf, const u16* __restrict__ vtg,
    const void* __restrict__ fcw, const void* __restrict__ fcb,
    void* __restrict__ out)
{
    __shared__ __align__(16) char smem[99840];
    // loop:    per-wave P slice [32][LDP] bf16-bits, 2560 B x 16 waves = 40960
    // combine: Cx f32 [512][24] at 0 (49152 B) -- sequential with P, barrier-split
    // epilog:  Ol f16 [32][LDO] at 49152 (16896 B); OutF f32 [32][LDO] at 66048 (33792 B)

    int fl = *flag;
    int t = threadIdx.x;
    int w = t >> 6, lane = t & 63;
    int quad = lane >> 4, l15 = lane & 15;
    int b = blockIdx.y, q0 = blockIdx.x * 32;
    int h = w & 7, khalf = w >> 3;

    u16* Pw = (u16*)(smem + w * 2560);

    float rsq[2];
    rsq[0] = rs[b*SQn + q0 + l15];
    rsq[1] = rs[b*SQn + q0 + 16 + l15];

    f16x8 aq[2];
    #pragma unroll
    for (int mt = 0; mt < 2; ++mt)
        aq[mt] = *(const f16x8*)(qf + (size_t)(b*SQn + q0 + mt*16 + l15)*DM + h*DH + quad*8);

    // ones-column B-fragment (bf16): B[k][0]=1, else 0 -> row-sum via MFMA
    u32 ov = (l15 == 0) ? 0x3F803F80u : 0u;
    u32x4 ovv = {ov, ov, ov, ov};
    s16x8 ones = __builtin_bit_cast(s16x8, ovv);

    const f32x4 fz = {0.f,0.f,0.f,0.f};
    f32x4 o[2][2] = {{fz,fz},{fz,fz}};
    f32x4 lacc[2] = {fz, fz};

    int kb0 = khalf * 1024;                      // this wave's half of the key range
    Frags cur = load_frags(kf, vtg, dist, fl, b, q0, h, kb0, l15, quad);

    for (int kt = 0; kt < 32; ++kt) {
        int kbn = kb0 + ((kt + 1) & 31) * 32;    // wrap inside own half: valid memory
        Frags nxt = load_frags(kf, vtg, dist, fl, b, q0, h, kbn, l15, quad);

        // S^T = K·Q^T : C elem (key = nt*16+quad*4+r, q = mt*16+l15)
        f32x4 st[2][2];
        #pragma unroll
        for (int mt = 0; mt < 2; ++mt)
            #pragma unroll
            for (int nt = 0; nt < 2; ++nt)
                st[mt][nt] = __builtin_amdgcn_mfma_f32_16x16x32_f16(cur.bk[nt], aq[mt], fz, 0, 0, 0);

        // dw (register-resident), exp (no max: bf16 P has f32 exponent range), pack, LDS
        #pragma unroll
        for (int mt = 0; mt < 2; ++mt)
            #pragma unroll
            for (int nt = 0; nt < 2; ++nt) {
                f32x4 d = cur.dd[mt][nt];
                u32 pb[4];
                #pragma unroll
                for (int r = 0; r < 4; ++r) {
                    float dwv = rsq[mt] * __builtin_amdgcn_rcpf(d[r] + 1e-9f);
                    float p = __expf(st[mt][nt][r] * dwv);
                    pb[r] = __builtin_bit_cast(u32, p);
                }
                u32x2 pk;
                pk[0] = __builtin_amdgcn_perm(pb[1], pb[0], 0x07060302u);  // [p1.hi16|p0.hi16]
                pk[1] = __builtin_amdgcn_perm(pb[3], pb[2], 0x07060302u);
                *(u32x2*)(Pw + (mt*16 + l15)*LDP + nt*16 + quad*4) = pk;
            }
        __asm__ __volatile__("" ::: "memory");   // order the per-wave LDS transpose

        // P @ [V | 1] in bf16 (l arrives in o's C-layout; same rounded p in num & denom)
        #pragma unroll
        for (int mt = 0; mt < 2; ++mt) {
            s16x8 ap = *(const s16x8*)(Pw + (mt*16 + l15)*LDP + quad*8);
            lacc[mt] = __builtin_amdgcn_mfma_f32_16x16x32_bf16(ap, ones, lacc[mt], 0, 0, 0);
            #pragma unroll
            for (int nt = 0; nt < 2; ++nt)
                o[mt][nt] = __builtin_amdgcn_mfma_f32_16x16x32_bf16(ap, cur.bv[nt], o[mt][nt], 0, 0, 0);
        }
        cur = nxt;
    }

    // ---- combine the two k-halves (plain sums: no-max softmax is linear in k) ----
    __syncthreads();                       // all waves done with P slices
    float* Cx = (float*)smem;              // [512][24] f32
    if (w >= 8) {
        float* dst = Cx + ((w - 8)*64 + lane)*24;
        *(f32x4*)(dst +  0) = o[0][0];
        *(f32x4*)(dst +  4) = o[0][1];
        *(f32x4*)(dst +  8) = o[1][0];
        *(f32x4*)(dst + 12) = o[1][1];
        *(f32x4*)(dst + 16) = lacc[0];
        *(f32x4*)(dst + 20) = lacc[1];
    }
    __syncthreads();
    f16* Ol = (f16*)(smem + OL_OFF);       // [32][LDO]
    if (w < 8) {
        const float* src = Cx + (w*64 + lane)*24;
        o[0][0] += *(const f32x4*)(src +  0);
        o[0][1] += *(const f32x4*)(src +  4);
        o[1][0] += *(const f32x4*)(src +  8);
        o[1][1] += *(const f32x4*)(src + 12);
        lacc[0] += *(const f32x4*)(src + 16);
        lacc[1] += *(const f32x4*)(src + 20);

        // normalize: l for row (mt,quad,r) lives at lane (l15=0, quad), col 0
        #pragma unroll
        for (int mt = 0; mt < 2; ++mt)
            #pragma unroll
            for (int r = 0; r < 4; ++r) {
                float lv = __shfl(lacc[mt][r], lane & 48);
                float inv = 1.0f / lv;
                o[mt][0][r] *= inv;
                o[mt][1][r] *= inv;
            }

        #pragma unroll
        for (int mt = 0; mt < 2; ++mt)
            #pragma unroll
            for (int nt = 0; nt < 2; ++nt)
                #pragma unroll
                for (int r = 0; r < 4; ++r)
                    Ol[(mt*16 + quad*4 + r)*LDO + h*DH + nt*16 + l15] = (f16)o[mt][nt][r];
    }
    __syncthreads();

    // ---- fused fc across all 16 waves: wave w owns output cols w*16..w*16+15 ----
    f32x4 c[2] = {fz, fz};
    int n = w*16 + l15;
    for (int ks = 0; ks < 8; ++ks) {
        f16x8 bw = ld8(fcw, (size_t)n*DM + ks*32 + quad*8, fl);
        #pragma unroll
        for (int mt = 0; mt < 2; ++mt) {
            f16x8 a2 = *(const f16x8*)(Ol + (mt*16 + l15)*LDO + ks*32 + quad*8);
            c[mt] = __builtin_amdgcn_mfma_f32_16x16x32_f16(a2, bw, c[mt], 0, 0, 0);
        }
    }
    float* OutF = (float*)(smem + OUTF_OFF);  // [32][LDO] f32
    {
        float bv = ld1(fcb, n, fl);
        #pragma unroll
        for (int mt = 0; mt < 2; ++mt)
            #pragma unroll
            for (int r = 0; r < 4; ++r)
                OutF[(mt*16 + quad*4 + r)*LDO + n] = c[mt][r] + bv;
    }
    __syncthreads();
    if (fl) {
        float* of = (float*)out;
        int row = t >> 5, col = (t & 31) * 8;
        f32x4 v0 = *(const f32x4*)(OutF + row*LDO + col);
        f32x4 v1 = *(const f32x4*)(OutF + row*LDO + col + 4);
        float* dst = of + ((size_t)(b*SQn + q0 + row))*DM + col;
        *(f32x4*)dst       = v0;
        *(f32x4*)(dst + 4) = v1;
    } else {
        u16* ob = (u16*)out;
        int row = t >> 5, col = (t & 31) * 8;
        f32x4 v0 = *(const f32x4*)(OutF + row*LDO + col);
        f32x4 v1 = *(const f32x4*)(OutF + row*LDO + col + 4);
        u32x4 pk;
        pk[0] = (u32)f2bf(v0[0]) | ((u32)f2bf(v0[1]) << 16);
        pk[1] = (u32)f2bf(v0[2]) | ((u32)f2bf(v0[3]) << 16);
        pk[2] = (u32)f2bf(v1[0]) | ((u32)f2bf(v1[1]) << 16);
        pk[3] = (u32)f2bf(v1[2]) | ((u32)f2bf(v1[3]) << 16);
        *(u32x4*)(ob + ((size_t)(b*SQn + q0 + row))*DM + col) = pk;
    }
}

// ---------------------------------------------------------------------------
extern "C" void kernel_launch(void* const* d_in, const int* in_sizes, int n_in,
                              void* d_out, int out_size, void* d_ws, size_t ws_size,
                              hipStream_t stream)
{
    const void* query  = d_in[0];
    const void* values = d_in[1];
    const void* dist   = d_in[2];
    const void* Wq     = d_in[3];
    const void* Wqb    = d_in[4];
    const void* Wk     = d_in[5];
    const void* Wkb    = d_in[6];
    const void* Wv     = d_in[7];
    const void* Wvb    = d_in[8];
    const void* fcw    = d_in[9];
    const void* fcb    = d_in[10];
    const void* tkeys  = d_in[11];

    char* ws   = (char*)d_ws;
    f16*  qf   = (f16*)ws;                     // 4 MB  [B*SQ][256] f16
    f16*  kf   = (f16*)(ws + (4u << 20));      // 1 MB  [S][256] f16
    u16*  vt   = (u16*)(ws + (5u << 20));      // 4 MB  [b][d][s] bf16
    float* rsp = (float*)(ws + (9u << 20));    // 32 KB [B*SQ]
    int*  flag = (int*)(ws + (9u << 20) + 32768);

    detect_kernel<<<1, 256, 0, stream>>>((const u32*)query, flag);
    proj_kernel<<<dim3(288, 4), 256, 0, stream>>>(flag, query, values, tkeys,
                                                  Wq, Wqb, Wk, Wkb, Wv, Wvb,
                                                  qf, kf, vt);
    dwsum_kernel<<<dim3(BB * SQn), 256, 0, stream>>>(flag, dist, rsp);
    attn_kernel<<<dim3(64, 4), 1024, 0, stream>>>(flag, dist, rsp, qf, kf, vt, fcw, fcb, d_out);
}

// Round 4
// 264.899 us; speedup vs baseline: 1.2411x; 1.1075x over previous
//
#include <hip/hip_runtime.h>

#define BB 4
#define SQn 2048
#define SS 2048
#define DM 256
#define DH 32

typedef unsigned short u16;
typedef unsigned int u32;
typedef _Float16 f16;
typedef __attribute__((ext_vector_type(8))) f16 f16x8;
typedef __attribute__((ext_vector_type(8))) short s16x8;
typedef __attribute__((ext_vector_type(4))) float f32x4;
typedef __attribute__((ext_vector_type(4))) u32 u32x4;
typedef __attribute__((ext_vector_type(2))) u32 u32x2;

__device__ __forceinline__ float bf2f(u16 x){ u32 u=((u32)x)<<16; return __builtin_bit_cast(float,u); }
__device__ __forceinline__ u16 f2bf(float f){ u32 u=__builtin_bit_cast(u32,f); u32 r=(u+0x7fffu+((u>>16)&1u))>>16; return (u16)r; }

// Load 8 consecutive elements as f16 from bf16 (fl=0) or fp32 (fl=1) buffer.
__device__ __forceinline__ f16x8 ld8(const void* p, size_t off, int fl)
{
    f16x8 r;
    if (fl) {
        const float* f = (const float*)p + off;
        f32x4 a = *(const f32x4*)f;
        f32x4 b = *(const f32x4*)(f + 4);
        #pragma unroll
        for (int i = 0; i < 4; ++i) { r[i] = (f16)a[i]; r[4+i] = (f16)b[i]; }
    } else {
        const u16* s = (const u16*)p + off;
        u32x4 v = *(const u32x4*)s;
        #pragma unroll
        for (int i = 0; i < 4; ++i) {
            u32 x = v[i];
            r[2*i]   = (f16)bf2f((u16)(x & 0xffff));
            r[2*i+1] = (f16)bf2f((u16)(x >> 16));
        }
    }
    return r;
}
__device__ __forceinline__ float ld1(const void* p, int idx, int fl)
{ return fl ? ((const float*)p)[idx] : bf2f(((const u16*)p)[idx]); }

// 4 consecutive f32 from bf16/fp32 buffer.
__device__ __forceinline__ f32x4 ld_d4(const void* p, int fl, size_t off)
{
    f32x4 r;
    if (fl) r = *(const f32x4*)((const float*)p + off);
    else {
        u32x2 v = *(const u32x2*)((const u16*)p + off);
        r[0]=bf2f((u16)(v[0]&0xffff)); r[1]=bf2f((u16)(v[0]>>16));
        r[2]=bf2f((u16)(v[1]&0xffff)); r[3]=bf2f((u16)(v[1]>>16));
    }
    return r;
}

// ---------------------------------------------------------------------------
// Dtype detection: 0 = bf16 inputs, 1 = fp32 inputs.
// ---------------------------------------------------------------------------
__global__ void detect_kernel(const u32* __restrict__ q, int* __restrict__ flag)
{
    int t = threadIdx.x;                 // 256
    u32 w = q[t];
    u32 e = (w >> 7) & 0xFFu;
    int vote = ((e >= 0x70u && e <= 0x85u) || ((w & 0xFFFFu) == 0u)) ? 1 : 0;
    #pragma unroll
    for (int d = 1; d < 64; d <<= 1) vote += __shfl_xor(vote, d);
    __shared__ int ps[4];
    if ((t & 63) == 0) ps[t >> 6] = vote;
    __syncthreads();
    if (t == 0) *flag = ((ps[0]+ps[1]+ps[2]+ps[3]) >= 128) ? 0 : 1;
}

// ---------------------------------------------------------------------------
// Kernel A: fused projections (f16 MFMA).  q->qf f16, k->kf f16,
// v->vt bf16 TRANSPOSED [b][d][s].
// ---------------------------------------------------------------------------
__global__ __launch_bounds__(256) void proj_kernel(
    const int* __restrict__ flag,
    const void* __restrict__ query, const void* __restrict__ values, const void* __restrict__ tkeys,
    const void* __restrict__ Wq, const void* __restrict__ Wqb,
    const void* __restrict__ Wk, const void* __restrict__ Wkb,
    const void* __restrict__ Wv, const void* __restrict__ Wvb,
    f16* __restrict__ qf, f16* __restrict__ kf, u16* __restrict__ vt)
{
    int fl = *flag;
    int bx = blockIdx.x;
    const void *X, *W, *Bi; int mode, rowbase;
    if (bx < 128)      { X=query;  W=Wq; Bi=Wqb; mode=0; rowbase=bx*64; }
    else if (bx < 256) { X=values; W=Wv; Bi=Wvb; mode=2; rowbase=(bx-128)*64; }
    else               { X=tkeys;  W=Wk; Bi=Wkb; mode=1; rowbase=(bx-256)*64; }
    int colbase = blockIdx.y * 64;

    __shared__ f16 Xs[64][40];
    __shared__ f16 Ws[64][40];
    __shared__ u16 Os[64][72];

    int t = threadIdx.x;
    int lane = t & 63, w = t >> 6;
    int quad = lane >> 4, l15 = lane & 15;

    const f32x4 fz = {0.f,0.f,0.f,0.f};
    f32x4 acc[4] = {fz,fz,fz,fz};

    for (int ks = 0; ks < 8; ++ks) {
        int k0 = ks * 32;
        {
            int row = t >> 2, ch = (t & 3) * 8;
            f16x8 xv = ld8(X, (size_t)(rowbase+row)*DM + k0 + ch, fl);
            f16x8 wv = ld8(W, (size_t)(colbase+row)*DM + k0 + ch, fl);
            *(f16x8*)(&Xs[row][ch]) = xv;
            *(f16x8*)(&Ws[row][ch]) = wv;
        }
        __syncthreads();
        f16x8 a = *(const f16x8*)(&Xs[w*16 + l15][quad*8]);
        #pragma unroll
        for (int nt = 0; nt < 4; ++nt) {
            f16x8 bfr = *(const f16x8*)(&Ws[nt*16 + l15][quad*8]);
            acc[nt] = __builtin_amdgcn_mfma_f32_16x16x32_f16(a, bfr, acc[nt], 0, 0, 0);
        }
        __syncthreads();
    }

    if (mode == 2) {
        // bf16 transposed store: (m, n) -> vt[(b*256+n)*2048 + s]
        #pragma unroll
        for (int nt = 0; nt < 4; ++nt) {
            int col = colbase + nt*16 + l15;
            float bv = ld1(Bi, col, fl);
            int m = rowbase + w*16 + quad*4;
            int b = m >> 11, s = m & 2047;
            u32x2 pk;
            pk[0] = (u32)f2bf(acc[nt][0]+bv) | ((u32)f2bf(acc[nt][1]+bv) << 16);
            pk[1] = (u32)f2bf(acc[nt][2]+bv) | ((u32)f2bf(acc[nt][3]+bv) << 16);
            *(u32x2*)(vt + ((size_t)(b*DM + col))*SS + s) = pk;
        }
    } else {
        f16* dst = (mode == 0) ? qf : kf;
        #pragma unroll
        for (int nt = 0; nt < 4; ++nt) {
            int col = nt*16 + l15;
            float bv = ld1(Bi, colbase + col, fl);
            #pragma unroll
            for (int r = 0; r < 4; ++r)
                Os[w*16 + quad*4 + r][col] = __builtin_bit_cast(u16, (f16)(acc[nt][r] + bv));
        }
        __syncthreads();
        #pragma unroll
        for (int p = 0; p < 2; ++p) {
            int rr = (t >> 3) + p*32;
            int ch = (t & 7) * 8;
            u32x4 v = *(const u32x4*)(&Os[rr][ch]);
            *(u32x4*)(dst + (size_t)(rowbase+rr)*DM + colbase + ch) = v;
        }
    }
}

// ---------------------------------------------------------------------------
// Kernel B: rs[row] = (1/sqrt(32)) / sum_k 1/(dist[row][k] + 1e-9)
// ---------------------------------------------------------------------------
__global__ __launch_bounds__(256) void dwsum_kernel(
    const int* __restrict__ flag, const void* __restrict__ dist, float* __restrict__ rs)
{
    int fl = *flag;
    int row = blockIdx.x;
    int t = threadIdx.x;
    float s = 0.f;
    if (fl) {
        const float* p = (const float*)dist + (size_t)row * SS + t*8;
        f32x4 a = *(const f32x4*)p;
        f32x4 b = *(const f32x4*)(p + 4);
        #pragma unroll
        for (int i = 0; i < 4; ++i) { s += 1.0f/(a[i]+1e-9f); s += 1.0f/(b[i]+1e-9f); }
    } else {
        const u16* p = (const u16*)dist + (size_t)row * SS + t*8;
        u32x4 v = *(const u32x4*)p;
        #pragma unroll
        for (int i = 0; i < 4; ++i) {
            u32 x = v[i];
            s += 1.0f / (bf2f((u16)(x & 0xffff)) + 1e-9f);
            s += 1.0f / (bf2f((u16)(x >> 16))    + 1e-9f);
        }
    }
    #pragma unroll
    for (int d = 1; d < 64; d <<= 1) s += __shfl_xor(s, d);
    __shared__ float ps[4];
    if ((t & 63) == 0) ps[t >> 6] = s;
    __syncthreads();
    if (t == 0) rs[row] = 0.17677669529663687f / (ps[0] + ps[1] + ps[2] + ps[3]);
}

// ---------------------------------------------------------------------------
// Kernel C: flash attention (no-max softmax, S^T orientation, zero in-loop
// barriers) + fused fc.  1 block = (b, 32 q-rows), 8 waves = 8 heads.
// Round-0 structure + EXPLICIT depth-2 software pipeline (4 slots, unroll-4)
// and __launch_bounds__(512,2) so the allocator has VGPR headroom to keep the
// prefetched Frags live (r0's VGPR=68 proved the compiler serialized loads).
// ---------------------------------------------------------------------------
#define LDP 40
#define LDO 264

struct Frags { f16x8 bk[2]; s16x8 bv[2]; f32x4 dd[2][2]; };

__device__ __forceinline__ Frags load_frags(
    const f16* kf, const u16* vtg, const void* dist, int fl,
    int b, int q0, int h, int kb, int l15, int quad)
{
    Frags f;
    #pragma unroll
    for (int nt = 0; nt < 2; ++nt)
        f.bk[nt] = *(const f16x8*)(kf + (size_t)(kb + nt*16 + l15)*DM + h*DH + quad*8);
    #pragma unroll
    for (int nt = 0; nt < 2; ++nt)
        f.bv[nt] = __builtin_bit_cast(s16x8,
            *(const u32x4*)(vtg + ((size_t)(b*DM + h*DH + nt*16 + l15))*SS + kb + quad*8));
    #pragma unroll
    for (int mt = 0; mt < 2; ++mt)
        #pragma unroll
        for (int nt = 0; nt < 2; ++nt)
            f.dd[mt][nt] = ld_d4(dist, fl,
                ((size_t)(b*SQn + q0 + mt*16 + l15))*SS + kb + nt*16 + quad*4);
    return f;
}

__device__ __forceinline__ void tile_compute(
    const Frags& F, const f16x8 (&aq)[2], const float (&rsq)[2], s16x8 ones,
    u16* Pw, int l15, int quad, f32x4 (&o)[2][2], f32x4 (&lacc)[2])
{
    const f32x4 fz = {0.f,0.f,0.f,0.f};

    // S^T = K·Q^T : C elem (key = nt*16+quad*4+r, q = mt*16+l15)
    f32x4 st[2][2];
    #pragma unroll
    for (int mt = 0; mt < 2; ++mt)
        #pragma unroll
        for (int nt = 0; nt < 2; ++nt)
            st[mt][nt] = __builtin_amdgcn_mfma_f32_16x16x32_f16(F.bk[nt], aq[mt], fz, 0, 0, 0);

    // dw (register-resident), exp (no max: bf16 P has f32 exponent range), pack, LDS
    #pragma unroll
    for (int mt = 0; mt < 2; ++mt)
        #pragma unroll
        for (int nt = 0; nt < 2; ++nt) {
            f32x4 d = F.dd[mt][nt];
            u32 pb[4];
            #pragma unroll
            for (int r = 0; r < 4; ++r) {
                float dwv = rsq[mt] * __builtin_amdgcn_rcpf(d[r] + 1e-9f);
                float p = __expf(st[mt][nt][r] * dwv);
                pb[r] = __builtin_bit_cast(u32, p);
            }
            u32x2 pk;
            pk[0] = __builtin_amdgcn_perm(pb[1], pb[0], 0x07060302u);  // [p1.hi16|p0.hi16]
            pk[1] = __builtin_amdgcn_perm(pb[3], pb[2], 0x07060302u);
            *(u32x2*)(Pw + (mt*16 + l15)*LDP + nt*16 + quad*4) = pk;
        }
    __asm__ __volatile__("" ::: "memory");   // order the per-wave LDS transpose

    // P @ [V | 1] in bf16 (l arrives in o's C-layout; same rounded p in num & denom)
    #pragma unroll
    for (int mt = 0; mt < 2; ++mt) {
        s16x8 ap = *(const s16x8*)(Pw + (mt*16 + l15)*LDP + quad*8);
        lacc[mt] = __builtin_amdgcn_mfma_f32_16x16x32_bf16(ap, ones, lacc[mt], 0, 0, 0);
        #pragma unroll
        for (int nt = 0; nt < 2; ++nt)
            o[mt][nt] = __builtin_amdgcn_mfma_f32_16x16x32_bf16(ap, F.bv[nt], o[mt][nt], 0, 0, 0);
    }
}

__global__ __launch_bounds__(512, 2) void attn_kernel(
    const int* __restrict__ flag,
    const void* __restrict__ dist, const float* __restrict__ rs,
    const f16* __restrict__ qf, const f16* __restrict__ kf, const u16* __restrict__ vtg,
    const void* __restrict__ fcw, const void* __restrict__ fcb,
    void* __restrict__ out)
{
    __shared__ __align__(16) char smem[55296];
    // loop phase: per-wave P slice [32][LDP] (bf16 bits), 2560 B each, 8 waves
    // epilogue:   Ol f16 [32][LDO] at 0 (16896 B); OutF f32 [32][LDO] at 21504

    int fl = *flag;
    int t = threadIdx.x;
    int w = t >> 6, lane = t & 63;
    int quad = lane >> 4, l15 = lane & 15;
    int b = blockIdx.y, q0 = blockIdx.x * 32;
    int h = w;

    u16* Pw = (u16*)(smem + w * 2560);

    float rsq[2];
    rsq[0] = rs[b*SQn + q0 + l15];
    rsq[1] = rs[b*SQn + q0 + 16 + l15];

    f16x8 aq[2];
    #pragma unroll
    for (int mt = 0; mt < 2; ++mt)
        aq[mt] = *(const f16x8*)(qf + (size_t)(b*SQn + q0 + mt*16 + l15)*DM + h*DH + quad*8);

    // ones-column B-fragment (bf16): B[k][0]=1, else 0 -> row-sum via MFMA
    u32 ov = (l15 == 0) ? 0x3F803F80u : 0u;
    u32x4 ovv = {ov, ov, ov, ov};
    s16x8 ones = __builtin_bit_cast(s16x8, ovv);

    const f32x4 fz = {0.f,0.f,0.f,0.f};
    f32x4 o[2][2] = {{fz,fz},{fz,fz}};
    f32x4 lacc[2] = {fz, fz};

    // ---- depth-2 software pipeline, 4 named slots, unroll-4 body ----
    Frags s0 = load_frags(kf, vtg, dist, fl, b, q0, h, 0,  l15, quad);
    Frags s1 = load_frags(kf, vtg, dist, fl, b, q0, h, 32, l15, quad);

    for (int kt = 0; kt < 64; kt += 4) {
        Frags s2 = load_frags(kf, vtg, dist, fl, b, q0, h, ((kt + 2) & 63) * 32, l15, quad);
        tile_compute(s0, aq, rsq, ones, Pw, l15, quad, o, lacc);
        Frags s3 = load_frags(kf, vtg, dist, fl, b, q0, h, ((kt + 3) & 63) * 32, l15, quad);
        tile_compute(s1, aq, rsq, ones, Pw, l15, quad, o, lacc);
        s0 = load_frags(kf, vtg, dist, fl, b, q0, h, ((kt + 4) & 63) * 32, l15, quad);
        tile_compute(s2, aq, rsq, ones, Pw, l15, quad, o, lacc);
        s1 = load_frags(kf, vtg, dist, fl, b, q0, h, ((kt + 5) & 63) * 32, l15, quad);
        tile_compute(s3, aq, rsq, ones, Pw, l15, quad, o, lacc);
    }

    // ---- normalize: l for row (mt,quad,r) lives at lane (l15=0, quad), col 0 ----
    #pragma unroll
    for (int mt = 0; mt < 2; ++mt)
        #pragma unroll
        for (int r = 0; r < 4; ++r) {
            float lv = __shfl(lacc[mt][r], lane & 48);
            float inv = 1.0f / lv;
            o[mt][0][r] *= inv;
            o[mt][1][r] *= inv;
        }

    // ---- epilogue: fused fc ----
    __syncthreads();                       // all waves done with P slices
    f16* Ol = (f16*)smem;                  // [32][LDO]
    #pragma unroll
    for (int mt = 0; mt < 2; ++mt)
        #pragma unroll
        for (int nt = 0; nt < 2; ++nt)
            #pragma unroll
            for (int r = 0; r < 4; ++r)
                Ol[(mt*16 + quad*4 + r)*LDO + h*DH + nt*16 + l15] = (f16)o[mt][nt][r];
    __syncthreads();

    f32x4 c[2][2] = {{fz,fz},{fz,fz}};
    for (int ks = 0; ks < 8; ++ks) {
        f16x8 a2[2];
        #pragma unroll
        for (int mt = 0; mt < 2; ++mt)
            a2[mt] = *(const f16x8*)(Ol + (mt*16 + l15)*LDO + ks*32 + quad*8);
        #pragma unroll
        for (int nt = 0; nt < 2; ++nt) {
            int n = w*32 + nt*16 + l15;
            f16x8 bw = ld8(fcw, (size_t)n*DM + ks*32 + quad*8, fl);
            #pragma unroll
            for (int mt = 0; mt < 2; ++mt)
                c[mt][nt] = __builtin_amdgcn_mfma_f32_16x16x32_f16(a2[mt], bw, c[mt][nt], 0, 0, 0);
        }
    }
    float* OutF = (float*)(smem + 21504);  // [32][LDO] f32, disjoint from Ol
    #pragma unroll
    for (int nt = 0; nt < 2; ++nt) {
        int n = w*32 + nt*16 + l15;
        float bv = ld1(fcb, n, fl);
        #pragma unroll
        for (int mt = 0; mt < 2; ++mt)
            #pragma unroll
            for (int r = 0; r < 4; ++r)
                OutF[(mt*16 + quad*4 + r)*LDO + n] = c[mt][nt][r] + bv;
    }
    __syncthreads();
    if (fl) {
        float* of = (float*)out;
        #pragma unroll
        for (int p = 0; p < 4; ++p) {
            int idx = (t + p*512) * 4;
            int row = idx >> 8, col = idx & 255;
            f32x4 v = *(const f32x4*)(OutF + row*LDO + col);
            *(f32x4*)(of + ((size_t)(b*SQn + q0 + row))*DM + col) = v;
        }
    } else {
        u16* ob = (u16*)out;
        #pragma unroll
        for (int p = 0; p < 2; ++p) {
            int idx = (t + p*512) * 8;
            int row = idx >> 8, col = idx & 255;
            f32x4 v0 = *(const f32x4*)(OutF + row*LDO + col);
            f32x4 v1 = *(const f32x4*)(OutF + row*LDO + col + 4);
            u32x4 pk;
            pk[0] = (u32)f2bf(v0[0]) | ((u32)f2bf(v0[1]) << 16);
            pk[1] = (u32)f2bf(v0[2]) | ((u32)f2bf(v0[3]) << 16);
            pk[2] = (u32)f2bf(v1[0]) | ((u32)f2bf(v1[1]) << 16);
            pk[3] = (u32)f2bf(v1[2]) | ((u32)f2bf(v1[3]) << 16);
            *(u32x4*)(ob + ((size_t)(b*SQn + q0 + row))*DM + col) = pk;
        }
    }
}

// ---------------------------------------------------------------------------
extern "C" void kernel_launch(void* const* d_in, const int* in_sizes, int n_in,
                              void* d_out, int out_size, void* d_ws, size_t ws_size,
                              hipStream_t stream)
{
    const void* query  = d_in[0];
    const void* values = d_in[1];
    const void* dist   = d_in[2];
    const void* Wq     = d_in[3];
    const void* Wqb    = d_in[4];
    const void* Wk     = d_in[5];
    const void* Wkb    = d_in[6];
    const void* Wv     = d_in[7];
    const void* Wvb    = d_in[8];
    const void* fcw    = d_in[9];
    const void* fcb    = d_in[10];
    const void* tkeys  = d_in[11];

    char* ws   = (char*)d_ws;
    f16*  qf   = (f16*)ws;                     // 4 MB  [B*SQ][256] f16
    f16*  kf   = (f16*)(ws + (4u << 20));      // 1 MB  [S][256] f16
    u16*  vt   = (u16*)(ws + (5u << 20));      // 4 MB  [b][d][s] bf16
    float* rsp = (float*)(ws + (9u << 20));    // 32 KB [B*SQ]
    int*  flag = (int*)(ws + (9u << 20) + 32768);

    detect_kernel<<<1, 256, 0, stream>>>((const u32*)query, flag);
    proj_kernel<<<dim3(288, 4), 256, 0, stream>>>(flag, query, values, tkeys,
                                                  Wq, Wqb, Wk, Wkb, Wv, Wvb,
                                                  qf, kf, vt);
    dwsum_kernel<<<dim3(BB * SQn), 256, 0, stream>>>(flag, dist, rsp);
    attn_kernel<<<dim3(64, 4), 512, 0, stream>>>(flag, dist, rsp, qf, kf, vt, fcw, fcb, d_out);
}

// Round 5
// 200.925 us; speedup vs baseline: 1.6362x; 1.3184x over previous
//
#include <hip/hip_runtime.h>

#define BB 4
#define SQn 2048
#define SS 2048
#define DM 256
#define DH 32

typedef unsigned short u16;
typedef unsigned int u32;
typedef _Float16 f16;
typedef __attribute__((ext_vector_type(8))) f16 f16x8;
typedef __attribute__((ext_vector_type(8))) short s16x8;
typedef __attribute__((ext_vector_type(4))) float f32x4;
typedef __attribute__((ext_vector_type(2))) float f32x2;
typedef __attribute__((ext_vector_type(4))) u32 u32x4;
typedef __attribute__((ext_vector_type(2))) u32 u32x2;

__device__ __forceinline__ float bf2f(u16 x){ u32 u=((u32)x)<<16; return __builtin_bit_cast(float,u); }
__device__ __forceinline__ u16 f2bf(float f){ u32 u=__builtin_bit_cast(u32,f); u32 r=(u+0x7fffu+((u>>16)&1u))>>16; return (u16)r; }

// Load 8 consecutive elements as f16 from bf16 (fl=0) or fp32 (fl=1) buffer.
__device__ __forceinline__ f16x8 ld8(const void* p, size_t off, int fl)
{
    f16x8 r;
    if (fl) {
        const float* f = (const float*)p + off;
        f32x4 a = *(const f32x4*)f;
        f32x4 b = *(const f32x4*)(f + 4);
        #pragma unroll
        for (int i = 0; i < 4; ++i) { r[i] = (f16)a[i]; r[4+i] = (f16)b[i]; }
    } else {
        const u16* s = (const u16*)p + off;
        u32x4 v = *(const u32x4*)s;
        #pragma unroll
        for (int i = 0; i < 4; ++i) {
            u32 x = v[i];
            r[2*i]   = (f16)bf2f((u16)(x & 0xffff));
            r[2*i+1] = (f16)bf2f((u16)(x >> 16));
        }
    }
    return r;
}
__device__ __forceinline__ float ld1(const void* p, int idx, int fl)
{ return fl ? ((const float*)p)[idx] : bf2f(((const u16*)p)[idx]); }

// 2 consecutive f32 from bf16/fp32 buffer.
__device__ __forceinline__ f32x2 ld_d2(const void* p, int fl, size_t off)
{
    f32x2 r;
    if (fl) r = *(const f32x2*)((const float*)p + off);
    else {
        u32 x = *(const u32*)((const u16*)p + off);
        r[0] = bf2f((u16)(x & 0xffff)); r[1] = bf2f((u16)(x >> 16));
    }
    return r;
}

// ---------------------------------------------------------------------------
// Dtype detection: 0 = bf16 inputs, 1 = fp32 inputs.
// ---------------------------------------------------------------------------
__global__ void detect_kernel(const u32* __restrict__ q, int* __restrict__ flag)
{
    int t = threadIdx.x;                 // 256
    u32 w = q[t];
    u32 e = (w >> 7) & 0xFFu;
    int vote = ((e >= 0x70u && e <= 0x85u) || ((w & 0xFFFFu) == 0u)) ? 1 : 0;
    #pragma unroll
    for (int d = 1; d < 64; d <<= 1) vote += __shfl_xor(vote, d);
    __shared__ int ps[4];
    if ((t & 63) == 0) ps[t >> 6] = vote;
    __syncthreads();
    if (t == 0) *flag = ((ps[0]+ps[1]+ps[2]+ps[3]) >= 128) ? 0 : 1;
}

// ---------------------------------------------------------------------------
// Kernel A: fused projections (f16 MFMA).
//   q -> qf f16 [s][256]                      (unchanged)
//   k -> kf2 f16 [h][s][32]                   (per-head contiguous: coalesced bk)
//   v -> vt2 bf16 [b][h][kt][nt][quad][l15][8] (MFMA-fragment order: coalesced bv)
// ---------------------------------------------------------------------------
__global__ __launch_bounds__(256) void proj_kernel(
    const int* __restrict__ flag,
    const void* __restrict__ query, const void* __restrict__ values, const void* __restrict__ tkeys,
    const void* __restrict__ Wq, const void* __restrict__ Wqb,
    const void* __restrict__ Wk, const void* __restrict__ Wkb,
    const void* __restrict__ Wv, const void* __restrict__ Wvb,
    f16* __restrict__ qf, f16* __restrict__ kf, u16* __restrict__ vt)
{
    int fl = *flag;
    int bx = blockIdx.x;
    const void *X, *W, *Bi; int mode, rowbase;
    if (bx < 128)      { X=query;  W=Wq; Bi=Wqb; mode=0; rowbase=bx*64; }
    else if (bx < 256) { X=values; W=Wv; Bi=Wvb; mode=2; rowbase=(bx-128)*64; }
    else               { X=tkeys;  W=Wk; Bi=Wkb; mode=1; rowbase=(bx-256)*64; }
    int colbase = blockIdx.y * 64;

    __shared__ f16 Xs[64][40];
    __shared__ f16 Ws[64][40];
    __shared__ u16 Os[64][72];

    int t = threadIdx.x;
    int lane = t & 63, w = t >> 6;
    int quad = lane >> 4, l15 = lane & 15;

    const f32x4 fz = {0.f,0.f,0.f,0.f};
    f32x4 acc[4] = {fz,fz,fz,fz};

    for (int ks = 0; ks < 8; ++ks) {
        int k0 = ks * 32;
        {
            int row = t >> 2, ch = (t & 3) * 8;
            f16x8 xv = ld8(X, (size_t)(rowbase+row)*DM + k0 + ch, fl);
            f16x8 wv = ld8(W, (size_t)(colbase+row)*DM + k0 + ch, fl);
            *(f16x8*)(&Xs[row][ch]) = xv;
            *(f16x8*)(&Ws[row][ch]) = wv;
        }
        __syncthreads();
        f16x8 a = *(const f16x8*)(&Xs[w*16 + l15][quad*8]);
        #pragma unroll
        for (int nt = 0; nt < 4; ++nt) {
            f16x8 bfr = *(const f16x8*)(&Ws[nt*16 + l15][quad*8]);
            acc[nt] = __builtin_amdgcn_mfma_f32_16x16x32_f16(a, bfr, acc[nt], 0, 0, 0);
        }
        __syncthreads();
    }

    if (mode == 2) {
        // vt2 fragment-interleaved store: element (m, col) ->
        //   idx = (((b*8+h)*64 + kt)*2 + ntv)*512 + qv*128 + (col&15)*8 + kk
        int m = rowbase + w*16 + quad*4;     // 4 consecutive seq positions
        int bb = m >> 11, s = m & 2047;
        int ktv = s >> 5, qv = (s >> 3) & 3, kk = s & 7;   // kk in {0,4}
        #pragma unroll
        for (int nt = 0; nt < 4; ++nt) {
            int col = colbase + nt*16 + l15;
            float bv = ld1(Bi, col, fl);
            int hv = col >> 5, ntv = (col >> 4) & 1;
            size_t idx = (((((size_t)(bb*8 + hv))*64 + ktv)*2 + ntv)*4 + qv)*128
                         + (size_t)(col & 15)*8 + kk;
            u32x2 pk;
            pk[0] = (u32)f2bf(acc[nt][0]+bv) | ((u32)f2bf(acc[nt][1]+bv) << 16);
            pk[1] = (u32)f2bf(acc[nt][2]+bv) | ((u32)f2bf(acc[nt][3]+bv) << 16);
            *(u32x2*)(vt + idx) = pk;
        }
    } else {
        #pragma unroll
        for (int nt = 0; nt < 4; ++nt) {
            int col = nt*16 + l15;
            float bv = ld1(Bi, colbase + col, fl);
            #pragma unroll
            for (int r = 0; r < 4; ++r)
                Os[w*16 + quad*4 + r][col] = __builtin_bit_cast(u16, (f16)(acc[nt][r] + bv));
        }
        __syncthreads();
        #pragma unroll
        for (int p = 0; p < 2; ++p) {
            int rr = (t >> 3) + p*32;
            int ch = (t & 7) * 8;
            u32x4 v = *(const u32x4*)(&Os[rr][ch]);
            if (mode == 0) {
                *(u32x4*)(qf + (size_t)(rowbase+rr)*DM + colbase + ch) = v;
            } else {
                int head = (colbase + ch) >> 5;
                int dh = ch & 31;
                *(u32x4*)(kf + (size_t)head*(SS*DH) + (size_t)(rowbase+rr)*DH + dh) = v;
            }
        }
    }
}

// ---------------------------------------------------------------------------
// Kernel B: rs[row] = (1/sqrt(32)) / sum_k 1/(dist[row][k] + 1e-9)
// ---------------------------------------------------------------------------
__global__ __launch_bounds__(256) void dwsum_kernel(
    const int* __restrict__ flag, const void* __restrict__ dist, float* __restrict__ rs)
{
    int fl = *flag;
    int row = blockIdx.x;
    int t = threadIdx.x;
    float s = 0.f;
    if (fl) {
        const float* p = (const float*)dist + (size_t)row * SS + t*8;
        f32x4 a = *(const f32x4*)p;
        f32x4 b = *(const f32x4*)(p + 4);
        #pragma unroll
        for (int i = 0; i < 4; ++i) { s += 1.0f/(a[i]+1e-9f); s += 1.0f/(b[i]+1e-9f); }
    } else {
        const u16* p = (const u16*)dist + (size_t)row * SS + t*8;
        u32x4 v = *(const u32x4*)p;
        #pragma unroll
        for (int i = 0; i < 4; ++i) {
            u32 x = v[i];
            s += 1.0f / (bf2f((u16)(x & 0xffff)) + 1e-9f);
            s += 1.0f / (bf2f((u16)(x >> 16))    + 1e-9f);
        }
    }
    #pragma unroll
    for (int d = 1; d < 64; d <<= 1) s += __shfl_xor(s, d);
    __shared__ float ps[4];
    if ((t & 63) == 0) ps[t >> 6] = s;
    __syncthreads();
    if (t == 0) rs[row] = 0.17677669529663687f / (ps[0] + ps[1] + ps[2] + ps[3]);
}

// ---------------------------------------------------------------------------
// Kernel C: flash attention (no-max softmax, S^T orientation) + fused fc.
// 1 block = (b, 32 q-rows), 8 waves = 8 heads.  All hot-loop global loads are
// single-segment coalesced (kf2/vt2 layouts); dist tile is LDS-staged once per
// block (kills the 8x per-wave gather that made r0-r4 memory-transaction-bound).
// ---------------------------------------------------------------------------
#define LDP 40
#define LDO 264
#define DB_OFF 20480
#define DB_LD 36

__global__ __launch_bounds__(512, 2) void attn_kernel(
    const int* __restrict__ flag,
    const void* __restrict__ dist, const float* __restrict__ rs,
    const f16* __restrict__ qf, const f16* __restrict__ kf, const u16* __restrict__ vtg,
    const void* __restrict__ fcw, const void* __restrict__ fcb,
    void* __restrict__ out)
{
    __shared__ __align__(16) char smem[55296];
    // loop:  P slices [8][32][LDP] at 0 (20480); dist dbuf 2x[32][36] f32 at 20480 (9216)
    // epi:   Ol f16 [32][LDO] at 0 (16896); OutF f32 [32][LDO] at 21504 (33792)

    int fl = *flag;
    int t = threadIdx.x;
    int w = t >> 6, lane = t & 63;
    int quad = lane >> 4, l15 = lane & 15;
    int b = blockIdx.y, q0 = blockIdx.x * 32;
    int h = w;

    u16* Pw = (u16*)(smem + w * 2560);
    float* db0 = (float*)(smem + DB_OFF);
    float* db1 = (float*)(smem + DB_OFF + 4608);

    float rsq[2];
    rsq[0] = rs[b*SQn + q0 + l15];
    rsq[1] = rs[b*SQn + q0 + 16 + l15];

    f16x8 aq[2];
    #pragma unroll
    for (int mt = 0; mt < 2; ++mt)
        aq[mt] = *(const f16x8*)(qf + (size_t)(b*SQn + q0 + mt*16 + l15)*DM + h*DH + quad*8);

    // ones-column B-fragment (bf16): B[k][0]=1, else 0 -> row-sum via MFMA
    u32 ov = (l15 == 0) ? 0x3F803F80u : 0u;
    u32x4 ovv = {ov, ov, ov, ov};
    s16x8 ones = __builtin_bit_cast(s16x8, ovv);

    const f32x4 fz = {0.f,0.f,0.f,0.f};
    f32x4 o[2][2] = {{fz,fz},{fz,fz}};
    f32x4 lacc[2] = {fz, fz};

    const f16* kfh = kf + (size_t)h * (SS*DH);
    const u16* vth = vtg + (((size_t)(b*8 + h)) << 16);   // * 64 kt * 1024 u16
    size_t dbase = (size_t)(b*SQn + q0 + (t >> 4)) * SS + (t & 15)*2;
    int drw = (t >> 4)*DB_LD + (t & 15)*2;                // LDS word offset (staging)

    // ---- prologue: stage dist tile 0; load K/V tile 0 ----
    {
        f32x2 sv = ld_d2(dist, fl, dbase);
        db0[drw] = sv[0]; db0[drw+1] = sv[1];
    }
    f16x8 ck[2]; s16x8 cv[2];
    #pragma unroll
    for (int nt = 0; nt < 2; ++nt) {
        ck[nt] = *(const f16x8*)(kfh + (size_t)(nt*16 + l15)*DH + quad*8);
        cv[nt] = __builtin_bit_cast(s16x8, *(const u32x4*)(vth + nt*512 + quad*128 + l15*8));
    }
    __syncthreads();

    for (int kt = 0; kt < 64; ++kt) {
        int ktn = (kt + 1) & 63;                 // wrap: last prefetch reads valid memory
        int kbn = ktn * 32;

        // issue next-tile loads early (hide under compute; barrier drains them)
        f32x2 sv = ld_d2(dist, fl, dbase + kbn);
        f16x8 nk[2]; s16x8 nv[2];
        #pragma unroll
        for (int nt = 0; nt < 2; ++nt) {
            nk[nt] = *(const f16x8*)(kfh + (size_t)(kbn + nt*16 + l15)*DH + quad*8);
            nv[nt] = __builtin_bit_cast(s16x8,
                *(const u32x4*)(vth + (size_t)ktn*1024 + nt*512 + quad*128 + l15*8));
        }

        // dist fragment from LDS (issued before MFMAs, consumed after)
        const float* dbc = (kt & 1) ? db1 : db0;
        f32x4 dd[2][2];
        #pragma unroll
        for (int mt = 0; mt < 2; ++mt)
            #pragma unroll
            for (int nt = 0; nt < 2; ++nt)
                dd[mt][nt] = *(const f32x4*)(dbc + (mt*16 + l15)*DB_LD + nt*16 + quad*4);

        // S^T = K·Q^T : C elem (key = nt*16+quad*4+r, q = mt*16+l15)
        f32x4 st[2][2];
        #pragma unroll
        for (int mt = 0; mt < 2; ++mt)
            #pragma unroll
            for (int nt = 0; nt < 2; ++nt)
                st[mt][nt] = __builtin_amdgcn_mfma_f32_16x16x32_f16(ck[nt], aq[mt], fz, 0, 0, 0);

        // dw, exp (no max: bf16 P has f32 exponent range), pack, per-wave LDS transpose
        #pragma unroll
        for (int mt = 0; mt < 2; ++mt)
            #pragma unroll
            for (int nt = 0; nt < 2; ++nt) {
                f32x4 d = dd[mt][nt];
                u32 pb[4];
                #pragma unroll
                for (int r = 0; r < 4; ++r) {
                    float dwv = rsq[mt] * __builtin_amdgcn_rcpf(d[r] + 1e-9f);
                    float p = __expf(st[mt][nt][r] * dwv);
                    pb[r] = __builtin_bit_cast(u32, p);
                }
                u32x2 pk;
                pk[0] = __builtin_amdgcn_perm(pb[1], pb[0], 0x07060302u);  // [p1.hi16|p0.hi16]
                pk[1] = __builtin_amdgcn_perm(pb[3], pb[2], 0x07060302u);
                *(u32x2*)(Pw + (mt*16 + l15)*LDP + nt*16 + quad*4) = pk;
            }
        __asm__ __volatile__("" ::: "memory");   // order the per-wave LDS transpose

        // P @ [V | 1] in bf16 (l arrives in o's C-layout; same rounded p in num & denom)
        #pragma unroll
        for (int mt = 0; mt < 2; ++mt) {
            s16x8 ap = *(const s16x8*)(Pw + (mt*16 + l15)*LDP + quad*8);
            lacc[mt] = __builtin_amdgcn_mfma_f32_16x16x32_bf16(ap, ones, lacc[mt], 0, 0, 0);
            #pragma unroll
            for (int nt = 0; nt < 2; ++nt)
                o[mt][nt] = __builtin_amdgcn_mfma_f32_16x16x32_bf16(ap, cv[nt], o[mt][nt], 0, 0, 0);
        }

        // write next dist tile into the other buffer; barrier publishes it
        float* dbn = (kt & 1) ? db0 : db1;
        dbn[drw] = sv[0]; dbn[drw+1] = sv[1];
        __syncthreads();

        ck[0] = nk[0]; ck[1] = nk[1]; cv[0] = nv[0]; cv[1] = nv[1];
    }

    // ---- normalize: l for row (mt,quad,r) lives at lane (l15=0, quad), col 0 ----
    #pragma unroll
    for (int mt = 0; mt < 2; ++mt)
        #pragma unroll
        for (int r = 0; r < 4; ++r) {
            float lv = __shfl(lacc[mt][r], lane & 48);
            float inv = 1.0f / lv;
            o[mt][0][r] *= inv;
            o[mt][1][r] *= inv;
        }

    // ---- epilogue: fused fc ----
    __syncthreads();                       // all waves done with P/dist slices
    f16* Ol = (f16*)smem;                  // [32][LDO]
    #pragma unroll
    for (int mt = 0; mt < 2; ++mt)
        #pragma unroll
        for (int nt = 0; nt < 2; ++nt)
            #pragma unroll
            for (int r = 0; r < 4; ++r)
                Ol[(mt*16 + quad*4 + r)*LDO + h*DH + nt*16 + l15] = (f16)o[mt][nt][r];
    __syncthreads();

    f32x4 c[2][2] = {{fz,fz},{fz,fz}};
    for (int ks = 0; ks < 8; ++ks) {
        f16x8 a2[2];
        #pragma unroll
        for (int mt = 0; mt < 2; ++mt)
            a2[mt] = *(const f16x8*)(Ol + (mt*16 + l15)*LDO + ks*32 + quad*8);
        #pragma unroll
        for (int nt = 0; nt < 2; ++nt) {
            int n = w*32 + nt*16 + l15;
            f16x8 bw = ld8(fcw, (size_t)n*DM + ks*32 + quad*8, fl);
            #pragma unroll
            for (int mt = 0; mt < 2; ++mt)
                c[mt][nt] = __builtin_amdgcn_mfma_f32_16x16x32_f16(a2[mt], bw, c[mt][nt], 0, 0, 0);
        }
    }
    float* OutF = (float*)(smem + 21504);  // [32][LDO] f32, disjoint from Ol
    #pragma unroll
    for (int nt = 0; nt < 2; ++nt) {
        int n = w*32 + nt*16 + l15;
        float bv = ld1(fcb, n, fl);
        #pragma unroll
        for (int mt = 0; mt < 2; ++mt)
            #pragma unroll
            for (int r = 0; r < 4; ++r)
                OutF[(mt*16 + quad*4 + r)*LDO + n] = c[mt][nt][r] + bv;
    }
    __syncthreads();
    if (fl) {
        float* of = (float*)out;
        #pragma unroll
        for (int p = 0; p < 4; ++p) {
            int idx = (t + p*512) * 4;
            int row = idx >> 8, col = idx & 255;
            f32x4 v = *(const f32x4*)(OutF + row*LDO + col);
            *(f32x4*)(of + ((size_t)(b*SQn + q0 + row))*DM + col) = v;
        }
    } else {
        u16* ob = (u16*)out;
        #pragma unroll
        for (int p = 0; p < 2; ++p) {
            int idx = (t + p*512) * 8;
            int row = idx >> 8, col = idx & 255;
            f32x4 v0 = *(const f32x4*)(OutF + row*LDO + col);
            f32x4 v1 = *(const f32x4*)(OutF + row*LDO + col + 4);
            u32x4 pk;
            pk[0] = (u32)f2bf(v0[0]) | ((u32)f2bf(v0[1]) << 16);
            pk[1] = (u32)f2bf(v0[2]) | ((u32)f2bf(v0[3]) << 16);
            pk[2] = (u32)f2bf(v1[0]) | ((u32)f2bf(v1[1]) << 16);
            pk[3] = (u32)f2bf(v1[2]) | ((u32)f2bf(v1[3]) << 16);
            *(u32x4*)(ob + ((size_t)(b*SQn + q0 + row))*DM + col) = pk;
        }
    }
}

// ---------------------------------------------------------------------------
extern "C" void kernel_launch(void* const* d_in, const int* in_sizes, int n_in,
                              void* d_out, int out_size, void* d_ws, size_t ws_size,
                              hipStream_t stream)
{
    const void* query  = d_in[0];
    const void* values = d_in[1];
    const void* dist   = d_in[2];
    const void* Wq     = d_in[3];
    const void* Wqb    = d_in[4];
    const void* Wk     = d_in[5];
    const void* Wkb    = d_in[6];
    const void* Wv     = d_in[7];
    const void* Wvb    = d_in[8];
    const void* fcw    = d_in[9];
    const void* fcb    = d_in[10];
    const void* tkeys  = d_in[11];

    char* ws   = (char*)d_ws;
    f16*  qf   = (f16*)ws;                     // 4 MB  [s][256] f16
    f16*  kf   = (f16*)(ws + (4u << 20));      // 1 MB  [h][s][32] f16
    u16*  vt   = (u16*)(ws + (5u << 20));      // 4 MB  [b][h][kt][nt][quad][l15][8] bf16
    float* rsp = (float*)(ws + (9u << 20));    // 32 KB [B*SQ]
    int*  flag = (int*)(ws + (9u << 20) + 32768);

    detect_kernel<<<1, 256, 0, stream>>>((const u32*)query, flag);
    proj_kernel<<<dim3(288, 4), 256, 0, stream>>>(flag, query, values, tkeys,
                                                  Wq, Wqb, Wk, Wkb, Wv, Wvb,
                                                  qf, kf, vt);
    dwsum_kernel<<<dim3(BB * SQn), 256, 0, stream>>>(flag, dist, rsp);
    attn_kernel<<<dim3(64, 4), 512, 0, stream>>>(flag, dist, rsp, qf, kf, vt, fcw, fcb, d_out);
}

// Round 6
// 196.504 us; speedup vs baseline: 1.6731x; 1.0225x over previous
//
#include <hip/hip_runtime.h>

#define BB 4
#define SQn 2048
#define SS 2048
#define DM 256
#define DH 32

typedef unsigned short u16;
typedef unsigned int u32;
typedef _Float16 f16;
typedef __attribute__((ext_vector_type(8))) f16 f16x8;
typedef __attribute__((ext_vector_type(8))) short s16x8;
typedef __attribute__((ext_vector_type(4))) float f32x4;
typedef __attribute__((ext_vector_type(2))) float f32x2;
typedef __attribute__((ext_vector_type(4))) u32 u32x4;
typedef __attribute__((ext_vector_type(2))) u32 u32x2;

__device__ __forceinline__ float bf2f(u16 x){ u32 u=((u32)x)<<16; return __builtin_bit_cast(float,u); }
__device__ __forceinline__ u16 f2bf(float f){ u32 u=__builtin_bit_cast(u32,f); u32 r=(u+0x7fffu+((u>>16)&1u))>>16; return (u16)r; }

// Load 8 consecutive elements as f16 from bf16 (fl=0) or fp32 (fl=1) buffer.
__device__ __forceinline__ f16x8 ld8(const void* p, size_t off, int fl)
{
    f16x8 r;
    if (fl) {
        const float* f = (const float*)p + off;
        f32x4 a = *(const f32x4*)f;
        f32x4 b = *(const f32x4*)(f + 4);
        #pragma unroll
        for (int i = 0; i < 4; ++i) { r[i] = (f16)a[i]; r[4+i] = (f16)b[i]; }
    } else {
        const u16* s = (const u16*)p + off;
        u32x4 v = *(const u32x4*)s;
        #pragma unroll
        for (int i = 0; i < 4; ++i) {
            u32 x = v[i];
            r[2*i]   = (f16)bf2f((u16)(x & 0xffff));
            r[2*i+1] = (f16)bf2f((u16)(x >> 16));
        }
    }
    return r;
}
__device__ __forceinline__ float ld1(const void* p, int idx, int fl)
{ return fl ? ((const float*)p)[idx] : bf2f(((const u16*)p)[idx]); }

// 2 consecutive f32 from bf16/fp32 buffer.
__device__ __forceinline__ f32x2 ld_d2(const void* p, int fl, size_t off)
{
    f32x2 r;
    if (fl) r = *(const f32x2*)((const float*)p + off);
    else {
        u32 x = *(const u32*)((const u16*)p + off);
        r[0] = bf2f((u16)(x & 0xffff)); r[1] = bf2f((u16)(x >> 16));
    }
    return r;
}

// ---------------------------------------------------------------------------
// Dtype detection: 0 = bf16 inputs, 1 = fp32 inputs.
// ---------------------------------------------------------------------------
__global__ void detect_kernel(const u32* __restrict__ q, int* __restrict__ flag)
{
    int t = threadIdx.x;                 // 256
    u32 w = q[t];
    u32 e = (w >> 7) & 0xFFu;
    int vote = ((e >= 0x70u && e <= 0x85u) || ((w & 0xFFFFu) == 0u)) ? 1 : 0;
    #pragma unroll
    for (int d = 1; d < 64; d <<= 1) vote += __shfl_xor(vote, d);
    __shared__ int ps[4];
    if ((t & 63) == 0) ps[t >> 6] = vote;
    __syncthreads();
    if (t == 0) *flag = ((ps[0]+ps[1]+ps[2]+ps[3]) >= 128) ? 0 : 1;
}

// ---------------------------------------------------------------------------
// Kernel A: fused projections (f16 MFMA).
//   q -> qf f16 [s][256]                      (unchanged)
//   k -> kf2 f16 [h][s][32]                   (per-head contiguous: coalesced bk)
//   v -> vt2 bf16 [b][h][kt][nt][quad][l15][8] (MFMA-fragment order: coalesced bv)
// ---------------------------------------------------------------------------
__global__ __launch_bounds__(256) void proj_kernel(
    const int* __restrict__ flag,
    const void* __restrict__ query, const void* __restrict__ values, const void* __restrict__ tkeys,
    const void* __restrict__ Wq, const void* __restrict__ Wqb,
    const void* __restrict__ Wk, const void* __restrict__ Wkb,
    const void* __restrict__ Wv, const void* __restrict__ Wvb,
    f16* __restrict__ qf, f16* __restrict__ kf, u16* __restrict__ vt)
{
    int fl = *flag;
    int bx = blockIdx.x;
    const void *X, *W, *Bi; int mode, rowbase;
    if (bx < 128)      { X=query;  W=Wq; Bi=Wqb; mode=0; rowbase=bx*64; }
    else if (bx < 256) { X=values; W=Wv; Bi=Wvb; mode=2; rowbase=(bx-128)*64; }
    else               { X=tkeys;  W=Wk; Bi=Wkb; mode=1; rowbase=(bx-256)*64; }
    int colbase = blockIdx.y * 64;

    __shared__ f16 Xs[64][40];
    __shared__ f16 Ws[64][40];
    __shared__ u16 Os[64][72];

    int t = threadIdx.x;
    int lane = t & 63, w = t >> 6;
    int quad = lane >> 4, l15 = lane & 15;

    const f32x4 fz = {0.f,0.f,0.f,0.f};
    f32x4 acc[4] = {fz,fz,fz,fz};

    for (int ks = 0; ks < 8; ++ks) {
        int k0 = ks * 32;
        {
            int row = t >> 2, ch = (t & 3) * 8;
            f16x8 xv = ld8(X, (size_t)(rowbase+row)*DM + k0 + ch, fl);
            f16x8 wv = ld8(W, (size_t)(colbase+row)*DM + k0 + ch, fl);
            *(f16x8*)(&Xs[row][ch]) = xv;
            *(f16x8*)(&Ws[row][ch]) = wv;
        }
        __syncthreads();
        f16x8 a = *(const f16x8*)(&Xs[w*16 + l15][quad*8]);
        #pragma unroll
        for (int nt = 0; nt < 4; ++nt) {
            f16x8 bfr = *(const f16x8*)(&Ws[nt*16 + l15][quad*8]);
            acc[nt] = __builtin_amdgcn_mfma_f32_16x16x32_f16(a, bfr, acc[nt], 0, 0, 0);
        }
        __syncthreads();
    }

    if (mode == 2) {
        // vt2 fragment-interleaved store: element (m, col) ->
        //   idx = (((b*8+h)*64 + kt)*2 + ntv)*512 + qv*128 + (col&15)*8 + kk
        int m = rowbase + w*16 + quad*4;     // 4 consecutive seq positions
        int bb = m >> 11, s = m & 2047;
        int ktv = s >> 5, qv = (s >> 3) & 3, kk = s & 7;   // kk in {0,4}
        #pragma unroll
        for (int nt = 0; nt < 4; ++nt) {
            int col = colbase + nt*16 + l15;
            float bv = ld1(Bi, col, fl);
            int hv = col >> 5, ntv = (col >> 4) & 1;
            size_t idx = (((((size_t)(bb*8 + hv))*64 + ktv)*2 + ntv)*4 + qv)*128
                         + (size_t)(col & 15)*8 + kk;
            u32x2 pk;
            pk[0] = (u32)f2bf(acc[nt][0]+bv) | ((u32)f2bf(acc[nt][1]+bv) << 16);
            pk[1] = (u32)f2bf(acc[nt][2]+bv) | ((u32)f2bf(acc[nt][3]+bv) << 16);
            *(u32x2*)(vt + idx) = pk;
        }
    } else {
        #pragma unroll
        for (int nt = 0; nt < 4; ++nt) {
            int col = nt*16 + l15;
            float bv = ld1(Bi, colbase + col, fl);
            #pragma unroll
            for (int r = 0; r < 4; ++r)
                Os[w*16 + quad*4 + r][col] = __builtin_bit_cast(u16, (f16)(acc[nt][r] + bv));
        }
        __syncthreads();
        #pragma unroll
        for (int p = 0; p < 2; ++p) {
            int rr = (t >> 3) + p*32;
            int ch = (t & 7) * 8;
            u32x4 v = *(const u32x4*)(&Os[rr][ch]);
            if (mode == 0) {
                *(u32x4*)(qf + (size_t)(rowbase+rr)*DM + colbase + ch) = v;
            } else {
                int head = (colbase + ch) >> 5;
                int dh = ch & 31;
                *(u32x4*)(kf + (size_t)head*(SS*DH) + (size_t)(rowbase+rr)*DH + dh) = v;
            }
        }
    }
}

// ---------------------------------------------------------------------------
// Kernel B: rs[row] = (1/sqrt(32)) / sum_k 1/(dist[row][k] + 1e-9)
// ---------------------------------------------------------------------------
__global__ __launch_bounds__(256) void dwsum_kernel(
    const int* __restrict__ flag, const void* __restrict__ dist, float* __restrict__ rs)
{
    int fl = *flag;
    int row = blockIdx.x;
    int t = threadIdx.x;
    float s = 0.f;
    if (fl) {
        const float* p = (const float*)dist + (size_t)row * SS + t*8;
        f32x4 a = *(const f32x4*)p;
        f32x4 b = *(const f32x4*)(p + 4);
        #pragma unroll
        for (int i = 0; i < 4; ++i) { s += 1.0f/(a[i]+1e-9f); s += 1.0f/(b[i]+1e-9f); }
    } else {
        const u16* p = (const u16*)dist + (size_t)row * SS + t*8;
        u32x4 v = *(const u32x4*)p;
        #pragma unroll
        for (int i = 0; i < 4; ++i) {
            u32 x = v[i];
            s += 1.0f / (bf2f((u16)(x & 0xffff)) + 1e-9f);
            s += 1.0f / (bf2f((u16)(x >> 16))    + 1e-9f);
        }
    }
    #pragma unroll
    for (int d = 1; d < 64; d <<= 1) s += __shfl_xor(s, d);
    __shared__ float ps[4];
    if ((t & 63) == 0) ps[t >> 6] = s;
    __syncthreads();
    if (t == 0) rs[row] = 0.17677669529663687f / (ps[0] + ps[1] + ps[2] + ps[3]);
}

// ---------------------------------------------------------------------------
// Kernel C: flash attention (no-max softmax, S^T orientation) + fused fc.
// 1 block = (b, 32 q-rows), 16 waves = 8 heads x 2 k-halves (no-max softmax is
// linear in k => plain-sum combine).  r5's coalesced kf2/vt2 + LDS-staged dist
// (2 tiles/iter, one per k-half group) + r3's verified combine/fc epilogue.
// 4 waves/SIMD to push the exp/pack VALU chain toward saturation.
// ---------------------------------------------------------------------------
#define LDP 40
#define LDO 264
#define DB_OFF 40960
#define DB_LD 36
#define OL_OFF  49152
#define OUTF_OFF 66048

__global__ __launch_bounds__(1024) void attn_kernel(
    const int* __restrict__ flag,
    const void* __restrict__ dist, const float* __restrict__ rs,
    const f16* __restrict__ qf, const f16* __restrict__ kf, const u16* __restrict__ vtg,
    const void* __restrict__ fcw, const void* __restrict__ fcb,
    void* __restrict__ out)
{
    __shared__ __align__(16) char smem[99840];
    // loop:   P slices [16][32][LDP] u16 at 0 (40960);
    //         dist dbuf 4x[32][36] f32 at 40960 (18432): buf (phase*2+group)
    // combine: Cx f32 [512][24] at 0 (49152)
    // epilog:  Ol f16 [32][LDO] at 49152 (16896); OutF f32 [32][LDO] at 66048 (33792)

    int fl = *flag;
    int t = threadIdx.x;
    int w = t >> 6, lane = t & 63;
    int quad = lane >> 4, l15 = lane & 15;
    int b = blockIdx.y, q0 = blockIdx.x * 32;
    int h = w & 7, khalf = w >> 3;

    u16* Pw = (u16*)(smem + w * 2560);
    float* dbB = (float*)(smem + DB_OFF);

    float rsq[2];
    rsq[0] = rs[b*SQn + q0 + l15];
    rsq[1] = rs[b*SQn + q0 + 16 + l15];

    f16x8 aq[2];
    #pragma unroll
    for (int mt = 0; mt < 2; ++mt)
        aq[mt] = *(const f16x8*)(qf + (size_t)(b*SQn + q0 + mt*16 + l15)*DM + h*DH + quad*8);

    // ones-column B-fragment (bf16): B[k][0]=1, else 0 -> row-sum via MFMA
    u32 ov = (l15 == 0) ? 0x3F803F80u : 0u;
    u32x4 ovv = {ov, ov, ov, ov};
    s16x8 ones = __builtin_bit_cast(s16x8, ovv);

    const f32x4 fz = {0.f,0.f,0.f,0.f};
    f32x4 o[2][2] = {{fz,fz},{fz,fz}};
    f32x4 lacc[2] = {fz, fz};

    const f16* kfh = kf + (size_t)h * (SS*DH);
    const u16* vth = vtg + (((size_t)(b*8 + h)) << 16);   // * 64 kt * 1024 u16

    // dist staging: thread group g (== its wave's khalf) stages that group's tile
    int g  = t >> 9;
    int tt = t & 511;
    int srow = tt >> 4, scol = (tt & 15) * 2;
    size_t dbase = (size_t)(b*SQn + q0 + srow)*SS + g*1024 + scol;
    int drw = srow*DB_LD + scol;

    // ---- prologue: stage dist tile 0 (both groups); load K/V tile 0 ----
    {
        f32x2 sv = ld_d2(dist, fl, dbase);
        float* d0 = dbB + g*1152;
        d0[drw] = sv[0]; d0[drw+1] = sv[1];
    }
    f16x8 ck[2]; s16x8 cv[2];
    {
        int ktg0 = khalf * 32;
        #pragma unroll
        for (int nt = 0; nt < 2; ++nt) {
            ck[nt] = *(const f16x8*)(kfh + (size_t)(ktg0*32 + nt*16 + l15)*DH + quad*8);
            cv[nt] = __builtin_bit_cast(s16x8,
                *(const u32x4*)(vth + (size_t)ktg0*1024 + nt*512 + quad*128 + l15*8));
        }
    }
    __syncthreads();

    for (int kt = 0; kt < 32; ++kt) {
        int ktn  = (kt + 1) & 31;                // wrap: last prefetch reads valid memory
        int ktgn = khalf*32 + ktn;

        // issue next-tile loads early (hide under compute; barrier drains them)
        f32x2 sv = ld_d2(dist, fl, dbase + (size_t)ktn*32);
        f16x8 nk[2]; s16x8 nv[2];
        #pragma unroll
        for (int nt = 0; nt < 2; ++nt) {
            nk[nt] = *(const f16x8*)(kfh + (size_t)(ktgn*32 + nt*16 + l15)*DH + quad*8);
            nv[nt] = __builtin_bit_cast(s16x8,
                *(const u32x4*)(vth + (size_t)ktgn*1024 + nt*512 + quad*128 + l15*8));
        }

        // dist fragment from LDS (this k-half's current buffer)
        const float* dbc = dbB + ((kt & 1)*2 + khalf)*1152;
        f32x4 dd[2][2];
        #pragma unroll
        for (int mt = 0; mt < 2; ++mt)
            #pragma unroll
            for (int nt = 0; nt < 2; ++nt)
                dd[mt][nt] = *(const f32x4*)(dbc + (mt*16 + l15)*DB_LD + nt*16 + quad*4);

        // S^T = K·Q^T : C elem (key = nt*16+quad*4+r, q = mt*16+l15)
        f32x4 st[2][2];
        #pragma unroll
        for (int mt = 0; mt < 2; ++mt)
            #pragma unroll
            for (int nt = 0; nt < 2; ++nt)
                st[mt][nt] = __builtin_amdgcn_mfma_f32_16x16x32_f16(ck[nt], aq[mt], fz, 0, 0, 0);

        // dw, exp (no max: bf16 P has f32 exponent range), pack, per-wave LDS transpose
        #pragma unroll
        for (int mt = 0; mt < 2; ++mt)
            #pragma unroll
            for (int nt = 0; nt < 2; ++nt) {
                f32x4 d = dd[mt][nt];
                u32 pb[4];
                #pragma unroll
                for (int r = 0; r < 4; ++r) {
                    float dwv = rsq[mt] * __builtin_amdgcn_rcpf(d[r] + 1e-9f);
                    float p = __expf(st[mt][nt][r] * dwv);
                    pb[r] = __builtin_bit_cast(u32, p);
                }
                u32x2 pk;
                pk[0] = __builtin_amdgcn_perm(pb[1], pb[0], 0x07060302u);  // [p1.hi16|p0.hi16]
                pk[1] = __builtin_amdgcn_perm(pb[3], pb[2], 0x07060302u);
                *(u32x2*)(Pw + (mt*16 + l15)*LDP + nt*16 + quad*4) = pk;
            }
        __asm__ __volatile__("" ::: "memory");   // order the per-wave LDS transpose

        // P @ [V | 1] in bf16 (l arrives in o's C-layout; same rounded p in num & denom)
        #pragma unroll
        for (int mt = 0; mt < 2; ++mt) {
            s16x8 ap = *(const s16x8*)(Pw + (mt*16 + l15)*LDP + quad*8);
            lacc[mt] = __builtin_amdgcn_mfma_f32_16x16x32_bf16(ap, ones, lacc[mt], 0, 0, 0);
            #pragma unroll
            for (int nt = 0; nt < 2; ++nt)
                o[mt][nt] = __builtin_amdgcn_mfma_f32_16x16x32_bf16(ap, cv[nt], o[mt][nt], 0, 0, 0);
        }

        // write next dist tile into the other phase buffer; barrier publishes it
        {
            float* dbn = dbB + (((kt + 1) & 1)*2 + g)*1152;
            dbn[drw] = sv[0]; dbn[drw+1] = sv[1];
        }
        __syncthreads();

        ck[0] = nk[0]; ck[1] = nk[1]; cv[0] = nv[0]; cv[1] = nv[1];
    }

    // ---- combine the two k-halves (plain sums: no-max softmax is linear in k) ----
    float* Cx = (float*)smem;              // [512][24] f32
    if (w >= 8) {
        float* dst = Cx + ((w - 8)*64 + lane)*24;
        *(f32x4*)(dst +  0) = o[0][0];
        *(f32x4*)(dst +  4) = o[0][1];
        *(f32x4*)(dst +  8) = o[1][0];
        *(f32x4*)(dst + 12) = o[1][1];
        *(f32x4*)(dst + 16) = lacc[0];
        *(f32x4*)(dst + 20) = lacc[1];
    }
    __syncthreads();
    f16* Ol = (f16*)(smem + OL_OFF);       // [32][LDO]
    if (w < 8) {
        const float* src = Cx + (w*64 + lane)*24;
        o[0][0] += *(const f32x4*)(src +  0);
        o[0][1] += *(const f32x4*)(src +  4);
        o[1][0] += *(const f32x4*)(src +  8);
        o[1][1] += *(const f32x4*)(src + 12);
        lacc[0] += *(const f32x4*)(src + 16);
        lacc[1] += *(const f32x4*)(src + 20);

        // normalize: l for row (mt,quad,r) lives at lane (l15=0, quad), col 0
        #pragma unroll
        for (int mt = 0; mt < 2; ++mt)
            #pragma unroll
            for (int r = 0; r < 4; ++r) {
                float lv = __shfl(lacc[mt][r], lane & 48);
                float inv = 1.0f / lv;
                o[mt][0][r] *= inv;
                o[mt][1][r] *= inv;
            }

        #pragma unroll
        for (int mt = 0; mt < 2; ++mt)
            #pragma unroll
            for (int nt = 0; nt < 2; ++nt)
                #pragma unroll
                for (int r = 0; r < 4; ++r)
                    Ol[(mt*16 + quad*4 + r)*LDO + h*DH + nt*16 + l15] = (f16)o[mt][nt][r];
    }
    __syncthreads();

    // ---- fused fc across all 16 waves: wave w owns output cols w*16..w*16+15 ----
    f32x4 c[2] = {fz, fz};
    int n = w*16 + l15;
    for (int ks = 0; ks < 8; ++ks) {
        f16x8 bw = ld8(fcw, (size_t)n*DM + ks*32 + quad*8, fl);
        #pragma unroll
        for (int mt = 0; mt < 2; ++mt) {
            f16x8 a2 = *(const f16x8*)(Ol + (mt*16 + l15)*LDO + ks*32 + quad*8);
            c[mt] = __builtin_amdgcn_mfma_f32_16x16x32_f16(a2, bw, c[mt], 0, 0, 0);
        }
    }
    float* OutF = (float*)(smem + OUTF_OFF);  // [32][LDO] f32
    {
        float bv = ld1(fcb, n, fl);
        #pragma unroll
        for (int mt = 0; mt < 2; ++mt)
            #pragma unroll
            for (int r = 0; r < 4; ++r)
                OutF[(mt*16 + quad*4 + r)*LDO + n] = c[mt][r] + bv;
    }
    __syncthreads();
    if (fl) {
        float* of = (float*)out;
        int row = t >> 5, col = (t & 31) * 8;
        f32x4 v0 = *(const f32x4*)(OutF + row*LDO + col);
        f32x4 v1 = *(const f32x4*)(OutF + row*LDO + col + 4);
        float* dst = of + ((size_t)(b*SQn + q0 + row))*DM + col;
        *(f32x4*)dst       = v0;
        *(f32x4*)(dst + 4) = v1;
    } else {
        u16* ob = (u16*)out;
        int row = t >> 5, col = (t & 31) * 8;
        f32x4 v0 = *(const f32x4*)(OutF + row*LDO + col);
        f32x4 v1 = *(const f32x4*)(OutF + row*LDO + col + 4);
        u32x4 pk;
        pk[0] = (u32)f2bf(v0[0]) | ((u32)f2bf(v0[1]) << 16);
        pk[1] = (u32)f2bf(v0[2]) | ((u32)f2bf(v0[3]) << 16);
        pk[2] = (u32)f2bf(v1[0]) | ((u32)f2bf(v1[1]) << 16);
        pk[3] = (u32)f2bf(v1[2]) | ((u32)f2bf(v1[3]) << 16);
        *(u32x4*)(ob + ((size_t)(b*SQn + q0 + row))*DM + col) = pk;
    }
}

// ---------------------------------------------------------------------------
extern "C" void kernel_launch(void* const* d_in, const int* in_sizes, int n_in,
                              void* d_out, int out_size, void* d_ws, size_t ws_size,
                              hipStream_t stream)
{
    const void* query  = d_in[0];
    const void* values = d_in[1];
    const void* dist   = d_in[2];
    const void* Wq     = d_in[3];
    const void* Wqb    = d_in[4];
    const void* Wk     = d_in[5];
    const void* Wkb    = d_in[6];
    const void* Wv     = d_in[7];
    const void* Wvb    = d_in[8];
    const void* fcw    = d_in[9];
    const void* fcb    = d_in[10];
    const void* tkeys  = d_in[11];

    char* ws   = (char*)d_ws;
    f16*  qf   = (f16*)ws;                     // 4 MB  [s][256] f16
    f16*  kf   = (f16*)(ws + (4u << 20));      // 1 MB  [h][s][32] f16
    u16*  vt   = (u16*)(ws + (5u << 20));      // 4 MB  [b][h][kt][nt][quad][l15][8] bf16
    float* rsp = (float*)(ws + (9u << 20));    // 32 KB [B*SQ]
    int*  flag = (int*)(ws + (9u << 20) + 32768);

    detect_kernel<<<1, 256, 0, stream>>>((const u32*)query, flag);
    proj_kernel<<<dim3(288, 4), 256, 0, stream>>>(flag, query, values, tkeys,
                                                  Wq, Wqb, Wk, Wkb, Wv, Wvb,
                                                  qf, kf, vt);
    dwsum_kernel<<<dim3(BB * SQn), 256, 0, stream>>>(flag, dist, rsp);
    attn_kernel<<<dim3(64, 4), 1024, 0, stream>>>(flag, dist, rsp, qf, kf, vt, fcw, fcb, d_out);
}